// Round 1
// baseline (1673.058 us; speedup 1.0000x reference)
//
#include <hip/hip_runtime.h>
#include <math.h>

#define NT 256

// ---------------- CSR build ----------------
__global__ __launch_bounds__(NT) void k_hist(const int* __restrict__ key, int* __restrict__ deg, int n) {
  int i = blockIdx.x * NT + threadIdx.x;
  if (i < n) atomicAdd(&deg[key[i]], 1);
}

__global__ __launch_bounds__(NT) void k_scan1(const int* __restrict__ in, int* __restrict__ out,
                                              int* __restrict__ aux, int n) {
  __shared__ int sd[NT];
  int t = threadIdx.x;
  int base = blockIdx.x * (NT * 8) + t * 8;
  int v[8], ex[8];
  int run = 0;
#pragma unroll
  for (int j = 0; j < 8; ++j) {
    v[j] = (base + j < n) ? in[base + j] : 0;
    ex[j] = run;
    run += v[j];
  }
  sd[t] = run;
  __syncthreads();
  for (int off = 1; off < NT; off <<= 1) {
    int x = (t >= off) ? sd[t - off] : 0;
    __syncthreads();
    sd[t] += x;
    __syncthreads();
  }
  int texcl = sd[t] - run;
#pragma unroll
  for (int j = 0; j < 8; ++j)
    if (base + j < n) out[base + j] = texcl + ex[j];
  if (t == NT - 1) aux[blockIdx.x] = sd[NT - 1];
}

__global__ __launch_bounds__(NT) void k_scan2(int* __restrict__ aux, int nb) {
  __shared__ int sd[NT];
  int t = threadIdx.x;
  int v = (t < nb) ? aux[t] : 0;
  sd[t] = v;
  __syncthreads();
  for (int off = 1; off < NT; off <<= 1) {
    int x = (t >= off) ? sd[t - off] : 0;
    __syncthreads();
    sd[t] += x;
    __syncthreads();
  }
  if (t < nb) aux[t] = sd[t] - v;  // exclusive
}

__global__ __launch_bounds__(NT) void k_scan3(int* __restrict__ out, const int* __restrict__ aux, int n) {
  int base = blockIdx.x * (NT * 8) + threadIdx.x * 8;
  int add = aux[blockIdx.x];
#pragma unroll
  for (int j = 0; j < 8; ++j)
    if (base + j < n) out[base + j] += add;
}

__global__ __launch_bounds__(NT) void k_scatter(const int* __restrict__ key, int* __restrict__ cursor,
                                                int* __restrict__ sorted, int n) {
  int i = blockIdx.x * NT + threadIdx.x;
  if (i < n) {
    int p = atomicAdd(&cursor[key[i]], 1);
    sorted[p] = i;
  }
}

// ---------------- GEMM: P[M,128] = A[M,128] @ W[128,128], fp32 ----------------
#define GBM 64
__global__ __launch_bounds__(NT) void k_gemm(const float* __restrict__ A, const float* __restrict__ W,
                                             float* __restrict__ P, int M) {
  __shared__ float Al[GBM][132];  // +4 pad: A-column reads conflict-free
  __shared__ float Wl[128][128];
  int tid = threadIdx.x;
  const float4* W4 = (const float4*)W;
#pragma unroll
  for (int i = 0; i < 16; ++i) {
    int idx = tid + i * NT;  // 0..4095
    int r = idx >> 5, c = (idx & 31) << 2;
    *(float4*)&Wl[r][c] = W4[idx];
  }
  long arow = (long)blockIdx.x * GBM;
  const float4* A4 = (const float4*)(A + arow * 128);
#pragma unroll
  for (int i = 0; i < 8; ++i) {
    int idx = tid + i * NT;  // 0..2047
    int r = idx >> 5, c = (idx & 31) << 2;
    float4 val = {0.f, 0.f, 0.f, 0.f};
    if (arow + r < M) val = A4[idx];
    *(float4*)&Al[r][c] = val;
  }
  __syncthreads();
  int tx = tid & 15, ty = tid >> 4;
  int tx4 = tx * 4, ty4 = ty * 4;
  float4 acc[4][2];
#pragma unroll
  for (int i = 0; i < 4; ++i) {
    acc[i][0] = {0.f, 0.f, 0.f, 0.f};
    acc[i][1] = {0.f, 0.f, 0.f, 0.f};
  }
#pragma unroll 4
  for (int k = 0; k < 128; ++k) {
    float4 w0 = *(const float4*)&Wl[k][tx4];
    float4 w1 = *(const float4*)&Wl[k][64 + tx4];
    float av[4] = {Al[ty4 + 0][k], Al[ty4 + 1][k], Al[ty4 + 2][k], Al[ty4 + 3][k]};
#pragma unroll
    for (int i = 0; i < 4; ++i) {
      acc[i][0].x += av[i] * w0.x;
      acc[i][0].y += av[i] * w0.y;
      acc[i][0].z += av[i] * w0.z;
      acc[i][0].w += av[i] * w0.w;
      acc[i][1].x += av[i] * w1.x;
      acc[i][1].y += av[i] * w1.y;
      acc[i][1].z += av[i] * w1.z;
      acc[i][1].w += av[i] * w1.w;
    }
  }
#pragma unroll
  for (int i = 0; i < 4; ++i) {
    long r = arow + ty4 + i;
    if (r < M) {
      *(float4*)&P[r * 128 + tx4] = acc[i][0];
      *(float4*)&P[r * 128 + 64 + tx4] = acc[i][1];
    }
  }
}

// ---------------- entity attention-aggregate + l2norm + residual ----------------
// one wave per head-segment; online softmax over the segment's edges
__global__ __launch_bounds__(NT) void k_entity(
    const float* __restrict__ P, const float* __restrict__ cur,
    const int* __restrict__ tail, const int* __restrict__ etype,
    const int* __restrict__ offs, const int* __restrict__ sorted,
    const float* __restrict__ rel_emb,
    float* __restrict__ next, float* __restrict__ res, int n_ent) {
  __shared__ float rel[9 * 128];
  for (int i = threadIdx.x; i < 9 * 128; i += NT) rel[i] = rel_emb[i];
  __syncthreads();
  int wid = (blockIdx.x * NT + threadIdx.x) >> 6;
  int lane = threadIdx.x & 63;
  if (wid >= n_ent) return;
  const float* Ph = P + (size_t)wid * 128;
  float q0 = Ph[lane], q1 = Ph[64 + lane];
  float m0 = -1e30f, m1 = -1e30f, s0 = 0.f, s1 = 0.f, a0 = 0.f, a1 = 0.f;
  int beg = offs[wid], end = offs[wid + 1];
  for (int idx = beg; idx < end; ++idx) {
    int e = sorted[idx];
    int t = tail[e];
    int r = etype[e] - 1;
    float r0 = rel[r * 128 + lane], r1 = rel[r * 128 + 64 + lane];
    const float* Pt = P + (size_t)t * 128;
    const float* Ct = cur + (size_t)t * 128;
    float k0 = Pt[lane] * r0, k1 = Pt[64 + lane] * r1;
    float v0 = Ct[lane] * r0, v1 = Ct[64 + lane] * r1;
    float p0 = q0 * k0, p1 = q1 * k1;
#pragma unroll
    for (int off = 32; off > 0; off >>= 1) {
      p0 += __shfl_xor(p0, off);
      p1 += __shfl_xor(p1, off);
    }
    p0 *= 0.125f;  // 1/sqrt(64)
    p1 *= 0.125f;
    float mn = fmaxf(m0, p0);
    float sc = __expf(m0 - mn);
    float e0 = __expf(p0 - mn);
    s0 = s0 * sc + e0;
    a0 = a0 * sc + v0 * e0;
    m0 = mn;
    mn = fmaxf(m1, p1);
    sc = __expf(m1 - mn);
    float e1 = __expf(p1 - mn);
    s1 = s1 * sc + e1;
    a1 = a1 * sc + v1 * e1;
    m1 = mn;
  }
  float g0 = a0 / fmaxf(s0, 1e-16f);
  float g1 = a1 / fmaxf(s1, 1e-16f);
  float nr = g0 * g0 + g1 * g1;
#pragma unroll
  for (int off = 32; off > 0; off >>= 1) nr += __shfl_xor(nr, off);
  float inv = 1.0f / fmaxf(sqrtf(nr), 1e-12f);
  g0 *= inv;
  g1 *= inv;
  size_t o = (size_t)wid * 128 + lane;
  if (next) {
    next[o] = g0;
    next[o + 64] = g1;
  }
  res[o] += g0;
  res[o + 64] += g1;
}

// ---------------- user aggregate + l2norm + residual ----------------
__global__ __launch_bounds__(NT) void k_user(
    const float* __restrict__ cur, const int* __restrict__ item,
    const float* __restrict__ w, const int* __restrict__ offs,
    const int* __restrict__ sorted, float* __restrict__ res, int n_users) {
  int wid = (blockIdx.x * NT + threadIdx.x) >> 6;
  int lane = threadIdx.x & 63;
  if (wid >= n_users) return;
  float a0 = 0.f, a1 = 0.f;
  int beg = offs[wid], end = offs[wid + 1];
  for (int idx = beg; idx < end; ++idx) {
    int e = sorted[idx];
    int it = item[e];
    float ww = w[e];
    const float* Ct = cur + (size_t)it * 128;
    a0 += ww * Ct[lane];
    a1 += ww * Ct[64 + lane];
  }
  float nr = a0 * a0 + a1 * a1;
#pragma unroll
  for (int off = 32; off > 0; off >>= 1) nr += __shfl_xor(nr, off);
  float inv = 1.0f / fmaxf(sqrtf(nr), 1e-12f);
  a0 *= inv;
  a1 *= inv;
  size_t o = (size_t)wid * 128 + lane;
  res[o] += a0;
  res[o + 64] += a1;
}

// ---------------- host ----------------
static void run_scan(int* deg, int* offs, int* aux, int n, hipStream_t s) {
  int nb = (n + NT * 8 - 1) / (NT * 8);
  k_scan1<<<nb, NT, 0, s>>>(deg, offs, aux, n);
  k_scan2<<<1, NT, 0, s>>>(aux, nb);
  k_scan3<<<nb, NT, 0, s>>>(offs, aux, n);
}

extern "C" void kernel_launch(void* const* d_in, const int* in_sizes, int n_in,
                              void* d_out, int out_size, void* d_ws, size_t ws_size,
                              hipStream_t stream) {
  const float* user_emb = (const float*)d_in[0];
  const float* entity_emb = (const float*)d_in[1];
  const int* edge_index = (const int*)d_in[2];
  const int* edge_type = (const int*)d_in[3];
  const int* inter_edge = (const int*)d_in[4];
  const float* inter_w = (const float*)d_in[5];
  const float* rel_emb = (const float*)d_in[6];
  const float* W_Q = (const float*)d_in[7];
  float* out = (float*)d_out;

  int n_users = in_sizes[0] / 128;
  int n_ent = in_sizes[1] / 128;
  int e_kg = in_sizes[3];
  int e_ui = in_sizes[5];
  const int* head = edge_index;
  const int* tail = edge_index + e_kg;
  const int* iu = inter_edge;          // users
  const int* ii = inter_edge + e_ui;   // items

  // workspace carve
  char* wp = (char*)d_ws;
  auto take = [&](size_t bytes) {
    char* p = wp;
    wp += (bytes + 255) & ~(size_t)255;
    return p;
  };
  float* P = (float*)take((size_t)n_ent * 128 * 4);
  float* NXT = (float*)take((size_t)n_ent * 128 * 4);
  int* deg_e = (int*)take((size_t)(n_ent + 1) * 4);
  int* offs_e = (int*)take((size_t)(n_ent + 1) * 4);
  int* cur_e = (int*)take((size_t)n_ent * 4);
  int* sort_e = (int*)take((size_t)e_kg * 4);
  int* deg_u = (int*)take((size_t)(n_users + 1) * 4);
  int* offs_u = (int*)take((size_t)(n_users + 1) * 4);
  int* cur_u = (int*)take((size_t)n_users * 4);
  int* sort_u = (int*)take((size_t)e_ui * 4);
  int* aux = (int*)take(1024);
  (void)ws_size;
  (void)n_in;
  (void)out_size;

  // init residuals: out = [entity_emb ; user_emb]
  hipMemcpyAsync(out, entity_emb, (size_t)n_ent * 128 * 4, hipMemcpyDeviceToDevice, stream);
  hipMemcpyAsync(out + (size_t)n_ent * 128, user_emb, (size_t)n_users * 128 * 4,
                 hipMemcpyDeviceToDevice, stream);

  // CSR build (shared by both hops)
  hipMemsetAsync(deg_e, 0, (size_t)(n_ent + 1) * 4, stream);
  hipMemsetAsync(deg_u, 0, (size_t)(n_users + 1) * 4, stream);
  k_hist<<<(e_kg + NT - 1) / NT, NT, 0, stream>>>(head, deg_e, e_kg);
  k_hist<<<(e_ui + NT - 1) / NT, NT, 0, stream>>>(iu, deg_u, e_ui);
  run_scan(deg_e, offs_e, aux, n_ent + 1, stream);
  run_scan(deg_u, offs_u, aux, n_users + 1, stream);
  hipMemcpyAsync(cur_e, offs_e, (size_t)n_ent * 4, hipMemcpyDeviceToDevice, stream);
  hipMemcpyAsync(cur_u, offs_u, (size_t)n_users * 4, hipMemcpyDeviceToDevice, stream);
  k_scatter<<<(e_kg + NT - 1) / NT, NT, 0, stream>>>(head, cur_e, sort_e, e_kg);
  k_scatter<<<(e_ui + NT - 1) / NT, NT, 0, stream>>>(iu, cur_u, sort_u, e_ui);

  // hops
  const float* cur = entity_emb;
  for (int hop = 0; hop < 2; ++hop) {
    k_gemm<<<(n_ent + GBM - 1) / GBM, NT, 0, stream>>>(cur, W_Q, P, n_ent);
    k_entity<<<(n_ent + 3) / 4, NT, 0, stream>>>(P, cur, tail, edge_type, offs_e, sort_e,
                                                 rel_emb, hop == 0 ? NXT : nullptr, out, n_ent);
    k_user<<<(n_users + 3) / 4, NT, 0, stream>>>(cur, ii, inter_w, offs_u, sort_u,
                                                 out + (size_t)n_ent * 128, n_users);
    cur = NXT;
  }
}

// Round 2
// 1286.472 us; speedup vs baseline: 1.3005x; 1.3005x over previous
//
#include <hip/hip_runtime.h>
#include <math.h>

#define NT 256

// ---------------- CSR build ----------------
__global__ __launch_bounds__(NT) void k_hist(const int* __restrict__ key, int* __restrict__ deg, int n) {
  int i = blockIdx.x * NT + threadIdx.x;
  if (i < n) atomicAdd(&deg[key[i]], 1);
}

__global__ __launch_bounds__(NT) void k_scan1(const int* __restrict__ in, int* __restrict__ out,
                                              int* __restrict__ aux, int n) {
  __shared__ int sd[NT];
  int t = threadIdx.x;
  int base = blockIdx.x * (NT * 8) + t * 8;
  int v[8], ex[8];
  int run = 0;
#pragma unroll
  for (int j = 0; j < 8; ++j) {
    v[j] = (base + j < n) ? in[base + j] : 0;
    ex[j] = run;
    run += v[j];
  }
  sd[t] = run;
  __syncthreads();
  for (int off = 1; off < NT; off <<= 1) {
    int x = (t >= off) ? sd[t - off] : 0;
    __syncthreads();
    sd[t] += x;
    __syncthreads();
  }
  int texcl = sd[t] - run;
#pragma unroll
  for (int j = 0; j < 8; ++j)
    if (base + j < n) out[base + j] = texcl + ex[j];
  if (t == NT - 1) aux[blockIdx.x] = sd[NT - 1];
}

__global__ __launch_bounds__(NT) void k_scan2(int* __restrict__ aux, int nb) {
  __shared__ int sd[NT];
  int t = threadIdx.x;
  int v = (t < nb) ? aux[t] : 0;
  sd[t] = v;
  __syncthreads();
  for (int off = 1; off < NT; off <<= 1) {
    int x = (t >= off) ? sd[t - off] : 0;
    __syncthreads();
    sd[t] += x;
    __syncthreads();
  }
  if (t < nb) aux[t] = sd[t] - v;  // exclusive
}

__global__ __launch_bounds__(NT) void k_scan3(int* __restrict__ out, const int* __restrict__ aux, int n) {
  int base = blockIdx.x * (NT * 8) + threadIdx.x * 8;
  int add = aux[blockIdx.x];
#pragma unroll
  for (int j = 0; j < 8; ++j)
    if (base + j < n) out[base + j] += add;
}

__global__ __launch_bounds__(NT) void k_scatter(const int* __restrict__ key, int* __restrict__ cursor,
                                                int* __restrict__ sorted, int n) {
  int i = blockIdx.x * NT + threadIdx.x;
  if (i < n) {
    int p = atomicAdd(&cursor[key[i]], 1);
    sorted[p] = i;
  }
}

// ---------------- GEMM: P[M,128] = A[M,128] @ W[128,128], fp32 ----------------
// 128x128 block tile, 8x8 per-thread register tile, XOR-swizzled A tile.
#define GBM 128
__global__ __launch_bounds__(NT) void k_gemm(const float* __restrict__ A, const float* __restrict__ W,
                                             float* __restrict__ P, int M) {
  __shared__ float Al[GBM][128];  // row r column-group c stored at c ^ (((r>>3)&3)<<2)
  __shared__ float Wl[128][128];
  int tid = threadIdx.x;
  const float4* W4 = (const float4*)W;
#pragma unroll
  for (int i = 0; i < 16; ++i) {
    int idx = tid + i * NT;  // 0..4095
    int r = idx >> 5, c = (idx & 31) << 2;
    *(float4*)&Wl[r][c] = W4[idx];
  }
  long arow = (long)blockIdx.x * GBM;
  const float4* A4 = (const float4*)(A + arow * 128);
#pragma unroll
  for (int i = 0; i < 16; ++i) {
    int idx = tid + i * NT;  // 0..4095
    int r = idx >> 5, c = (idx & 31) << 2;
    float4 val = {0.f, 0.f, 0.f, 0.f};
    if (arow + r < M) val = A4[idx];
    int cs = c ^ (((r >> 3) & 3) << 2);
    *(float4*)&Al[r][cs] = val;
  }
  __syncthreads();
  int tx4 = (tid & 15) * 4;   // cols tx4..tx4+3 and 64+tx4..64+tx4+3
  int ty8 = (tid >> 4) * 8;   // rows ty8..ty8+7
  float4 acc[8][2];
#pragma unroll
  for (int i = 0; i < 8; ++i) {
    acc[i][0] = {0.f, 0.f, 0.f, 0.f};
    acc[i][1] = {0.f, 0.f, 0.f, 0.f};
  }
  for (int kc = 0; kc < 32; ++kc) {
    int k4 = kc * 4;
    float4 a4[8];
#pragma unroll
    for (int i = 0; i < 8; ++i) {
      int r = ty8 + i;
      a4[i] = *(const float4*)&Al[r][k4 ^ (((r >> 3) & 3) << 2)];
    }
#pragma unroll
    for (int j = 0; j < 4; ++j) {
      float4 wa = *(const float4*)&Wl[k4 + j][tx4];
      float4 wb = *(const float4*)&Wl[k4 + j][64 + tx4];
#pragma unroll
      for (int i = 0; i < 8; ++i) {
        float av = ((const float*)&a4[i])[j];
        acc[i][0].x += av * wa.x;
        acc[i][0].y += av * wa.y;
        acc[i][0].z += av * wa.z;
        acc[i][0].w += av * wa.w;
        acc[i][1].x += av * wb.x;
        acc[i][1].y += av * wb.y;
        acc[i][1].z += av * wb.z;
        acc[i][1].w += av * wb.w;
      }
    }
  }
#pragma unroll
  for (int i = 0; i < 8; ++i) {
    long r = arow + ty8 + i;
    if (r < M) {
      *(float4*)&P[r * 128 + tx4] = acc[i][0];
      *(float4*)&P[r * 128 + 64 + tx4] = acc[i][1];
    }
  }
}

// ---------------- entity attention-aggregate + l2norm + residual ----------------
// one wave per head-segment; each 32-lane half processes a different edge
// (float4/lane over 128 channels); online softmax state per lane for its head;
// halves merged at the end.
__global__ __launch_bounds__(NT) void k_entity(
    const float* __restrict__ P, const float* __restrict__ cur,
    const int* __restrict__ tail, const int* __restrict__ etype,
    const int* __restrict__ offs, const int* __restrict__ sorted,
    const float* __restrict__ rel_emb, const float* __restrict__ base,
    float* __restrict__ next, float* __restrict__ res, int n_ent) {
  __shared__ float4 rel[9 * 32];
  for (int i = threadIdx.x; i < 9 * 32; i += NT) rel[i] = ((const float4*)rel_emb)[i];
  __syncthreads();
  int wid = (blockIdx.x * NT + threadIdx.x) >> 6;
  int lane = threadIdx.x & 63;
  if (wid >= n_ent) return;
  int half = lane >> 5;  // which edge slot
  int sub = lane & 31;   // channel group: floats sub*4..sub*4+3; head = sub>>4
  const float4* P4 = (const float4*)P;
  const float4* C4 = (const float4*)cur;
  float4 q = P4[(size_t)wid * 32 + sub];
  float m = -1e30f, s = 0.f;
  float4 a = {0.f, 0.f, 0.f, 0.f};
  int beg = offs[wid], end = offs[wid + 1];
  int idx = beg + half;
  int e = (idx < end) ? sorted[idx] : 0;
  while (idx < end) {
    int enext = (idx + 2 < end) ? sorted[idx + 2] : 0;
    int t = tail[e];
    int r = etype[e] - 1;
    float4 rr = rel[r * 32 + sub];
    float4 pt = P4[(size_t)t * 32 + sub];
    float4 ct = C4[(size_t)t * 32 + sub];
    float p = q.x * pt.x * rr.x + q.y * pt.y * rr.y + q.z * pt.z * rr.z + q.w * pt.w * rr.w;
    p += __shfl_xor(p, 1);
    p += __shfl_xor(p, 2);
    p += __shfl_xor(p, 4);
    p += __shfl_xor(p, 8);
    p *= 0.125f;  // 1/sqrt(64)
    float mn = fmaxf(m, p);
    float sc = __expf(m - mn);
    float ep = __expf(p - mn);
    s = s * sc + ep;
    a.x = a.x * sc + ct.x * rr.x * ep;
    a.y = a.y * sc + ct.y * rr.y * ep;
    a.z = a.z * sc + ct.z * rr.z * ep;
    a.w = a.w * sc + ct.w * rr.w * ep;
    m = mn;
    e = enext;
    idx += 2;
  }
  // merge the two halves' online-softmax states
  float mo = __shfl_xor(m, 32);
  float so = __shfl_xor(s, 32);
  float M = fmaxf(m, mo);
  float e0 = __expf(m - M);
  float e1 = __expf(mo - M);
  float S = s * e0 + so * e1;
  a.x *= e0; a.y *= e0; a.z *= e0; a.w *= e0;
  a.x += __shfl_xor(a.x, 32);
  a.y += __shfl_xor(a.y, 32);
  a.z += __shfl_xor(a.z, 32);
  a.w += __shfl_xor(a.w, 32);
  float invs = 1.0f / fmaxf(S, 1e-16f);
  float4 g = {a.x * invs, a.y * invs, a.z * invs, a.w * invs};
  float nr = g.x * g.x + g.y * g.y + g.z * g.z + g.w * g.w;
  nr += __shfl_xor(nr, 1);
  nr += __shfl_xor(nr, 2);
  nr += __shfl_xor(nr, 4);
  nr += __shfl_xor(nr, 8);
  nr += __shfl_xor(nr, 16);
  float inv = 1.0f / fmaxf(sqrtf(nr), 1e-12f);
  g.x *= inv; g.y *= inv; g.z *= inv; g.w *= inv;
  if (half == 0) {
    size_t o = (size_t)wid * 32 + sub;
    if (next) ((float4*)next)[o] = g;
    float4 r0 = base ? ((const float4*)base)[o] : ((const float4*)res)[o];
    r0.x += g.x; r0.y += g.y; r0.z += g.z; r0.w += g.w;
    ((float4*)res)[o] = r0;
  }
}

// ---------------- user aggregate + l2norm + residual ----------------
__global__ __launch_bounds__(NT) void k_user(
    const float* __restrict__ cur, const int* __restrict__ item,
    const float* __restrict__ w, const int* __restrict__ offs,
    const int* __restrict__ sorted, const float* __restrict__ base,
    float* __restrict__ res, int n_users) {
  int wid = (blockIdx.x * NT + threadIdx.x) >> 6;
  int lane = threadIdx.x & 63;
  if (wid >= n_users) return;
  int half = lane >> 5;
  int sub = lane & 31;
  const float4* C4 = (const float4*)cur;
  float4 a = {0.f, 0.f, 0.f, 0.f};
  int beg = offs[wid], end = offs[wid + 1];
  int idx = beg + half;
  int e = (idx < end) ? sorted[idx] : 0;
  while (idx < end) {
    int enext = (idx + 2 < end) ? sorted[idx + 2] : 0;
    int it = item[e];
    float ww = w[e];
    float4 c = C4[(size_t)it * 32 + sub];
    a.x += ww * c.x;
    a.y += ww * c.y;
    a.z += ww * c.z;
    a.w += ww * c.w;
    e = enext;
    idx += 2;
  }
  a.x += __shfl_xor(a.x, 32);
  a.y += __shfl_xor(a.y, 32);
  a.z += __shfl_xor(a.z, 32);
  a.w += __shfl_xor(a.w, 32);
  float nr = a.x * a.x + a.y * a.y + a.z * a.z + a.w * a.w;
  nr += __shfl_xor(nr, 1);
  nr += __shfl_xor(nr, 2);
  nr += __shfl_xor(nr, 4);
  nr += __shfl_xor(nr, 8);
  nr += __shfl_xor(nr, 16);
  float inv = 1.0f / fmaxf(sqrtf(nr), 1e-12f);
  if (half == 0) {
    size_t o = (size_t)wid * 32 + sub;
    float4 r0 = base ? ((const float4*)base)[o] : ((const float4*)res)[o];
    r0.x += a.x * inv;
    r0.y += a.y * inv;
    r0.z += a.z * inv;
    r0.w += a.w * inv;
    ((float4*)res)[o] = r0;
  }
}

// ---------------- host ----------------
static void run_scan(int* deg, int* offs, int* aux, int n, hipStream_t s) {
  int nb = (n + NT * 8 - 1) / (NT * 8);
  k_scan1<<<nb, NT, 0, s>>>(deg, offs, aux, n);
  k_scan2<<<1, NT, 0, s>>>(aux, nb);
  k_scan3<<<nb, NT, 0, s>>>(offs, aux, n);
}

extern "C" void kernel_launch(void* const* d_in, const int* in_sizes, int n_in,
                              void* d_out, int out_size, void* d_ws, size_t ws_size,
                              hipStream_t stream) {
  const float* user_emb = (const float*)d_in[0];
  const float* entity_emb = (const float*)d_in[1];
  const int* edge_index = (const int*)d_in[2];
  const int* edge_type = (const int*)d_in[3];
  const int* inter_edge = (const int*)d_in[4];
  const float* inter_w = (const float*)d_in[5];
  const float* rel_emb = (const float*)d_in[6];
  const float* W_Q = (const float*)d_in[7];
  float* out = (float*)d_out;

  int n_users = in_sizes[0] / 128;
  int n_ent = in_sizes[1] / 128;
  int e_kg = in_sizes[3];
  int e_ui = in_sizes[5];
  const int* head = edge_index;
  const int* tail = edge_index + e_kg;
  const int* iu = inter_edge;         // users
  const int* ii = inter_edge + e_ui;  // items

  // workspace carve
  char* wp = (char*)d_ws;
  auto take = [&](size_t bytes) {
    char* p = wp;
    wp += (bytes + 255) & ~(size_t)255;
    return p;
  };
  float* P = (float*)take((size_t)n_ent * 128 * 4);
  float* NXT = (float*)take((size_t)n_ent * 128 * 4);
  int* deg_e = (int*)take((size_t)(n_ent + 1) * 4);
  int* offs_e = (int*)take((size_t)(n_ent + 1) * 4);
  int* cur_e = (int*)take((size_t)n_ent * 4);
  int* sort_e = (int*)take((size_t)e_kg * 4);
  int* deg_u = (int*)take((size_t)(n_users + 1) * 4);
  int* offs_u = (int*)take((size_t)(n_users + 1) * 4);
  int* cur_u = (int*)take((size_t)n_users * 4);
  int* sort_u = (int*)take((size_t)e_ui * 4);
  int* aux = (int*)take(1024);
  (void)ws_size;
  (void)n_in;
  (void)out_size;

  // CSR build (shared by both hops)
  hipMemsetAsync(deg_e, 0, (size_t)(n_ent + 1) * 4, stream);
  hipMemsetAsync(deg_u, 0, (size_t)(n_users + 1) * 4, stream);
  k_hist<<<(e_kg + NT - 1) / NT, NT, 0, stream>>>(head, deg_e, e_kg);
  k_hist<<<(e_ui + NT - 1) / NT, NT, 0, stream>>>(iu, deg_u, e_ui);
  run_scan(deg_e, offs_e, aux, n_ent + 1, stream);
  run_scan(deg_u, offs_u, aux, n_users + 1, stream);
  hipMemcpyAsync(cur_e, offs_e, (size_t)n_ent * 4, hipMemcpyDeviceToDevice, stream);
  hipMemcpyAsync(cur_u, offs_u, (size_t)n_users * 4, hipMemcpyDeviceToDevice, stream);
  k_scatter<<<(e_kg + NT - 1) / NT, NT, 0, stream>>>(head, cur_e, sort_e, e_kg);
  k_scatter<<<(e_ui + NT - 1) / NT, NT, 0, stream>>>(iu, cur_u, sort_u, e_ui);

  // hops (residual init fused into hop-0 epilogues via `base` pointers)
  float* res_e = out;
  float* res_u = out + (size_t)n_ent * 128;
  const float* cur = entity_emb;
  for (int hop = 0; hop < 2; ++hop) {
    const float* base_e = (hop == 0) ? entity_emb : nullptr;
    const float* base_u = (hop == 0) ? user_emb : nullptr;
    k_gemm<<<(n_ent + GBM - 1) / GBM, NT, 0, stream>>>(cur, W_Q, P, n_ent);
    k_entity<<<(n_ent + 3) / 4, NT, 0, stream>>>(P, cur, tail, edge_type, offs_e, sort_e,
                                                 rel_emb, base_e, hop == 0 ? NXT : nullptr,
                                                 res_e, n_ent);
    k_user<<<(n_users + 3) / 4, NT, 0, stream>>>(cur, ii, inter_w, offs_u, sort_u,
                                                 base_u, res_u, n_users);
    cur = NXT;
  }
}

// Round 3
// 862.395 us; speedup vs baseline: 1.9400x; 1.4917x over previous
//
#include <hip/hip_runtime.h>
#include <math.h>

#define NT 256
typedef unsigned short u16;
typedef __attribute__((ext_vector_type(8))) u16 u16x8;
typedef __attribute__((ext_vector_type(4))) u16 u16x4;
typedef __attribute__((ext_vector_type(8))) short bf16x8;
typedef __attribute__((ext_vector_type(4))) float f32x4;

__device__ __forceinline__ float bf2f(u16 h) {
  union { unsigned u; float f; } v;
  v.u = ((unsigned)h) << 16;
  return v.f;
}
__device__ __forceinline__ u16 f2bf(float f) {
  union { float f; unsigned u; } v;
  v.f = f;
  unsigned r = v.u + 0x7FFFu + ((v.u >> 16) & 1u);
  return (u16)(r >> 16);
}

// ---------------- CSR build ----------------
__global__ __launch_bounds__(NT) void k_hist(const int* __restrict__ key, int* __restrict__ deg, int n) {
  int i = blockIdx.x * NT + threadIdx.x;
  if (i < n) atomicAdd(&deg[key[i]], 1);
}

__global__ __launch_bounds__(NT) void k_scan1(const int* __restrict__ in, int* __restrict__ out,
                                              int* __restrict__ aux, int n) {
  __shared__ int sd[NT];
  int t = threadIdx.x;
  int base = blockIdx.x * (NT * 8) + t * 8;
  int v[8], ex[8];
  int run = 0;
#pragma unroll
  for (int j = 0; j < 8; ++j) {
    v[j] = (base + j < n) ? in[base + j] : 0;
    ex[j] = run;
    run += v[j];
  }
  sd[t] = run;
  __syncthreads();
  for (int off = 1; off < NT; off <<= 1) {
    int x = (t >= off) ? sd[t - off] : 0;
    __syncthreads();
    sd[t] += x;
    __syncthreads();
  }
  int texcl = sd[t] - run;
#pragma unroll
  for (int j = 0; j < 8; ++j)
    if (base + j < n) out[base + j] = texcl + ex[j];
  if (t == NT - 1) aux[blockIdx.x] = sd[NT - 1];
}

__global__ __launch_bounds__(NT) void k_scan2(int* __restrict__ aux, int nb) {
  __shared__ int sd[NT];
  int t = threadIdx.x;
  int v = (t < nb) ? aux[t] : 0;
  sd[t] = v;
  __syncthreads();
  for (int off = 1; off < NT; off <<= 1) {
    int x = (t >= off) ? sd[t - off] : 0;
    __syncthreads();
    sd[t] += x;
    __syncthreads();
  }
  if (t < nb) aux[t] = sd[t] - v;  // exclusive
}

__global__ __launch_bounds__(NT) void k_scan3(int* __restrict__ out, const int* __restrict__ aux, int n) {
  int base = blockIdx.x * (NT * 8) + threadIdx.x * 8;
  int add = aux[blockIdx.x];
#pragma unroll
  for (int j = 0; j < 8; ++j)
    if (base + j < n) out[base + j] += add;
}

// scatter packed payloads (kills the sorted->edge->tail indirection)
__global__ __launch_bounds__(NT) void k_scatter_kg(const int* __restrict__ head, const int* __restrict__ tail,
                                                   const int* __restrict__ etype, int* __restrict__ cursor,
                                                   int* __restrict__ te_s, int n) {
  int i = blockIdx.x * NT + threadIdx.x;
  if (i < n) {
    int p = atomicAdd(&cursor[head[i]], 1);
    te_s[p] = tail[i] | ((etype[i] - 1) << 20);
  }
}

__global__ __launch_bounds__(NT) void k_scatter_ui(const int* __restrict__ usr, const int* __restrict__ item,
                                                   const float* __restrict__ w, int* __restrict__ cursor,
                                                   int* __restrict__ iw_s, int n) {
  int i = blockIdx.x * NT + threadIdx.x;
  if (i < n) {
    int p = atomicAdd(&cursor[usr[i]], 1);
    int wq = (int)(w[i] * 16383.0f + 0.5f);
    if (wq > 16383) wq = 16383;
    iw_s[p] = (int)(((unsigned)item[i]) | (((unsigned)wq) << 18));
  }
}

// ---------------- convert fp32 embeddings -> cur-half of PC (bf16) ----------------
__global__ __launch_bounds__(NT) void k_cvt(const float* __restrict__ src, u16* __restrict__ dst, int n_ent) {
  long i = (long)blockIdx.x * NT + threadIdx.x;
  if (i >= (long)n_ent * 32) return;
  long row = i >> 5;
  int c4 = (int)(i & 31) * 4;
  float4 v = *(const float4*)(src + row * 128 + c4);
  u16x4 o = {f2bf(v.x), f2bf(v.y), f2bf(v.z), f2bf(v.w)};
  *(u16x4*)(dst + row * 256 + 128 + c4) = o;
}

// ---------------- MFMA GEMM: P-half(PC) = cur-half(PC) @ W, bf16 in/out ----------------
__global__ __launch_bounds__(NT) void k_gemm(const u16* __restrict__ PCin, const float* __restrict__ W,
                                             u16* __restrict__ PCout, int M) {
  __shared__ u16 WT[128 * 136];  // W^T[n][k], pad 136 -> 2-way (free) bank aliasing on b128 reads
  for (int i = threadIdx.x; i < 128 * 128; i += NT) {
    int k = i >> 7, n = i & 127;
    WT[n * 136 + k] = f2bf(W[i]);
  }
  __syncthreads();
  int lane = threadIdx.x & 63;
  int l15 = lane & 15, l4 = lane >> 4;
  int wave = blockIdx.x * (NT / 64) + (threadIdx.x >> 6);
  int nw = gridDim.x * (NT / 64);
  int ntiles = (M + 15) >> 4;
  for (int tile = wave; tile < ntiles; tile += nw) {
    long row0 = (long)tile * 16;
    long ar = row0 + l15;
    if (ar > (long)M - 1) ar = (long)M - 1;
    const u16* arow = PCin + ar * 256 + 128;  // cur half
    bf16x8 af[4];
#pragma unroll
    for (int kk = 0; kk < 4; ++kk) af[kk] = *(const bf16x8*)(arow + kk * 32 + l4 * 8);
    f32x4 acc[8];
#pragma unroll
    for (int nt = 0; nt < 8; ++nt) acc[nt] = (f32x4){0.f, 0.f, 0.f, 0.f};
#pragma unroll
    for (int kk = 0; kk < 4; ++kk) {
#pragma unroll
      for (int nt = 0; nt < 8; ++nt) {
        bf16x8 bf = *(const bf16x8*)&WT[(nt * 16 + l15) * 136 + kk * 32 + l4 * 8];
        acc[nt] = __builtin_amdgcn_mfma_f32_16x16x32_bf16(af[kk], bf, acc[nt], 0, 0, 0);
      }
    }
#pragma unroll
    for (int nt = 0; nt < 8; ++nt) {
#pragma unroll
      for (int j = 0; j < 4; ++j) {
        long row = row0 + l4 * 4 + j;
        if (row < M) PCout[row * 256 + nt * 16 + l15] = f2bf(acc[nt][j]);
      }
    }
  }
}

// ---------------- entity attention-aggregate + l2norm + residual ----------------
// 32-lane group per edge (2 per wave). Lanes 0..15: P channels (score side);
// lanes 16..31: cur channels (value side). One 512B contiguous gather per edge.
__global__ __launch_bounds__(NT) void k_entity(
    const u16* __restrict__ PC, const int* __restrict__ offs, const int* __restrict__ te_s,
    const float* __restrict__ rel_emb, const float* __restrict__ base,
    u16* __restrict__ nextPC, float* __restrict__ res, int n_ent) {
  __shared__ float rel[9 * 128];
  for (int i = threadIdx.x; i < 9 * 128; i += NT) rel[i] = rel_emb[i];
  __syncthreads();
  int wid = (blockIdx.x * NT + threadIdx.x) >> 6;
  int lane = threadIdx.x & 63;
  if (wid >= n_ent) return;
  int half = lane >> 5;
  int g = lane & 31;
  int cl = g & 15;
  int chbase = cl * 8;  // channel base within P- or cur-side
  const u16x8* PC8 = (const u16x8*)PC;  // 32 x 16B chunks per entity
  // q: P chunk cl of the segment's head entity (valid data on all lanes; used by score math)
  u16x8 qh = PC8[(size_t)wid * 32 + cl];
  float q[8];
#pragma unroll
  for (int j = 0; j < 8; ++j) q[j] = bf2f(qh[j]);
  float m = -1e30f, s = 0.f;
  float a[8] = {0.f, 0.f, 0.f, 0.f, 0.f, 0.f, 0.f, 0.f};
  int beg = offs[wid], end = offs[wid + 1];
  int idx = beg + half;
  int te = (idx < end) ? te_s[idx] : 0;
  while (idx < end) {
    int ten = (idx + 2 < end) ? te_s[idx + 2] : 0;
    int t = te & 0xFFFFF;
    int r = te >> 20;
    u16x8 dh = PC8[(size_t)t * 32 + g];  // P chunk on lanes 0..15, cur chunk on 16..31
    const float* rp = &rel[r * 128 + chbase];
    float rl[8];
    *(float4*)rl = *(const float4*)rp;
    *(float4*)(rl + 4) = *(const float4*)(rp + 4);
    float x[8];
#pragma unroll
    for (int j = 0; j < 8; ++j) x[j] = bf2f(dh[j]);
    float pp = 0.f;
#pragma unroll
    for (int j = 0; j < 8; ++j) pp += q[j] * x[j] * rl[j];  // garbage on cur lanes, never read
    pp += __shfl_xor(pp, 1);
    pp += __shfl_xor(pp, 2);
    pp += __shfl_xor(pp, 4);
    float score = __shfl(pp, lane & 40) * 0.125f;  // broadcast from P-side head group
    float mn = fmaxf(m, score);
    float scl = __expf(m - mn);
    float ep = __expf(score - mn);
    s = s * scl + ep;
#pragma unroll
    for (int j = 0; j < 8; ++j) a[j] = a[j] * scl + x[j] * rl[j] * ep;
    m = mn;
    te = ten;
    idx += 2;
  }
  // merge the two halves' online-softmax states
  float mo = __shfl_xor(m, 32), so = __shfl_xor(s, 32);
  float M_ = fmaxf(m, mo);
  float e0 = __expf(m - M_), e1 = __expf(mo - M_);
  float S = s * e0 + so * e1;
  float gv[8];
#pragma unroll
  for (int j = 0; j < 8; ++j) {
    float b = a[j] * e0;
    b += __shfl_xor(b, 32);
    gv[j] = b;
  }
  float invs = 1.0f / fmaxf(S, 1e-16f);
  float nr = 0.f;
#pragma unroll
  for (int j = 0; j < 8; ++j) {
    gv[j] *= invs;
    nr += gv[j] * gv[j];
  }
  nr += __shfl_xor(nr, 1);
  nr += __shfl_xor(nr, 2);
  nr += __shfl_xor(nr, 4);
  nr += __shfl_xor(nr, 8);  // sum over the 16 value lanes (sides don't mix)
  float inv = 1.0f / fmaxf(sqrtf(nr), 1e-12f);
  if (lane >= 16 && lane < 32) {  // half-0 value lanes own channels chbase..chbase+7
#pragma unroll
    for (int j = 0; j < 8; ++j) gv[j] *= inv;
    if (nextPC) {
      u16x8 o;
#pragma unroll
      for (int j = 0; j < 8; ++j) o[j] = f2bf(gv[j]);
      ((u16x8*)nextPC)[(size_t)wid * 32 + g] = o;  // cur-half chunk
    }
    size_t o4 = (size_t)wid * 128 + chbase;
    const float* bp = base ? (base + o4) : (res + o4);
    float4 r0 = *(const float4*)bp;
    float4 r1 = *(const float4*)(bp + 4);
    r0.x += gv[0]; r0.y += gv[1]; r0.z += gv[2]; r0.w += gv[3];
    r1.x += gv[4]; r1.y += gv[5]; r1.z += gv[6]; r1.w += gv[7];
    *(float4*)(res + o4) = r0;
    *(float4*)(res + o4 + 4) = r1;
  }
}

// ---------------- user aggregate + l2norm + residual ----------------
__global__ __launch_bounds__(NT) void k_user(
    const u16* __restrict__ PC, const int* __restrict__ iw_s, const int* __restrict__ offs,
    const float* __restrict__ base, float* __restrict__ res, int n_users) {
  int wid = (blockIdx.x * NT + threadIdx.x) >> 6;
  int lane = threadIdx.x & 63;
  if (wid >= n_users) return;
  int half = lane >> 5;
  int g = lane & 31;
  const u16x4* PC4 = (const u16x4*)PC;  // 64 x 8B chunks per entity; cur = 32..63
  float a[4] = {0.f, 0.f, 0.f, 0.f};
  int beg = offs[wid], end = offs[wid + 1];
  int idx = beg + half;
  int iw = (idx < end) ? iw_s[idx] : 0;
  while (idx < end) {
    int iwn = (idx + 2 < end) ? iw_s[idx + 2] : 0;
    unsigned v = (unsigned)iw;
    int t = (int)(v & 0x3FFFFu);
    float ww = (float)(v >> 18) * (1.0f / 16383.0f);
    u16x4 d = PC4[(size_t)t * 64 + 32 + g];
    a[0] += ww * bf2f(d[0]);
    a[1] += ww * bf2f(d[1]);
    a[2] += ww * bf2f(d[2]);
    a[3] += ww * bf2f(d[3]);
    iw = iwn;
    idx += 2;
  }
#pragma unroll
  for (int j = 0; j < 4; ++j) a[j] += __shfl_xor(a[j], 32);
  float nr = a[0] * a[0] + a[1] * a[1] + a[2] * a[2] + a[3] * a[3];
  nr += __shfl_xor(nr, 1);
  nr += __shfl_xor(nr, 2);
  nr += __shfl_xor(nr, 4);
  nr += __shfl_xor(nr, 8);
  nr += __shfl_xor(nr, 16);
  float inv = 1.0f / fmaxf(sqrtf(nr), 1e-12f);
  if (half == 0) {
    size_t o = (size_t)wid * 128 + g * 4;
    const float* bp = base ? (base + o) : (res + o);
    float4 r0 = *(const float4*)bp;
    r0.x += a[0] * inv;
    r0.y += a[1] * inv;
    r0.z += a[2] * inv;
    r0.w += a[3] * inv;
    *(float4*)(res + o) = r0;
  }
}

// ---------------- host ----------------
static void run_scan(int* deg, int* offs, int* aux, int n, hipStream_t s) {
  int nb = (n + NT * 8 - 1) / (NT * 8);
  k_scan1<<<nb, NT, 0, s>>>(deg, offs, aux, n);
  k_scan2<<<1, NT, 0, s>>>(aux, nb);
  k_scan3<<<nb, NT, 0, s>>>(offs, aux, n);
}

extern "C" void kernel_launch(void* const* d_in, const int* in_sizes, int n_in,
                              void* d_out, int out_size, void* d_ws, size_t ws_size,
                              hipStream_t stream) {
  const float* user_emb = (const float*)d_in[0];
  const float* entity_emb = (const float*)d_in[1];
  const int* edge_index = (const int*)d_in[2];
  const int* edge_type = (const int*)d_in[3];
  const int* inter_edge = (const int*)d_in[4];
  const float* inter_w = (const float*)d_in[5];
  const float* rel_emb = (const float*)d_in[6];
  const float* W_Q = (const float*)d_in[7];
  float* out = (float*)d_out;

  int n_users = in_sizes[0] / 128;
  int n_ent = in_sizes[1] / 128;
  int e_kg = in_sizes[3];
  int e_ui = in_sizes[5];
  const int* head = edge_index;
  const int* tail = edge_index + e_kg;
  const int* iu = inter_edge;         // users
  const int* ii = inter_edge + e_ui;  // items

  // workspace carve
  char* wp = (char*)d_ws;
  auto take = [&](size_t bytes) {
    char* p = wp;
    wp += (bytes + 255) & ~(size_t)255;
    return p;
  };
  u16* PCa = (u16*)take((size_t)n_ent * 256 * 2);
  u16* PCb = (u16*)take((size_t)n_ent * 256 * 2);
  int* deg_e = (int*)take((size_t)(n_ent + 1) * 4);
  int* offs_e = (int*)take((size_t)(n_ent + 1) * 4);
  int* cur_e = (int*)take((size_t)n_ent * 4);
  int* te_s = (int*)take((size_t)e_kg * 4);
  int* deg_u = (int*)take((size_t)(n_users + 1) * 4);
  int* offs_u = (int*)take((size_t)(n_users + 1) * 4);
  int* cur_u = (int*)take((size_t)n_users * 4);
  int* iw_s = (int*)take((size_t)e_ui * 4);
  int* aux = (int*)take(1024);
  (void)ws_size;
  (void)n_in;
  (void)out_size;

  // cur-half of PCa <- entity_emb (bf16)
  k_cvt<<<(n_ent * 32 + NT - 1) / NT, NT, 0, stream>>>(entity_emb, PCa, n_ent);

  // CSR build (shared by both hops), payload-packed
  hipMemsetAsync(deg_e, 0, (size_t)(n_ent + 1) * 4, stream);
  hipMemsetAsync(deg_u, 0, (size_t)(n_users + 1) * 4, stream);
  k_hist<<<(e_kg + NT - 1) / NT, NT, 0, stream>>>(head, deg_e, e_kg);
  k_hist<<<(e_ui + NT - 1) / NT, NT, 0, stream>>>(iu, deg_u, e_ui);
  run_scan(deg_e, offs_e, aux, n_ent + 1, stream);
  run_scan(deg_u, offs_u, aux, n_users + 1, stream);
  hipMemcpyAsync(cur_e, offs_e, (size_t)n_ent * 4, hipMemcpyDeviceToDevice, stream);
  hipMemcpyAsync(cur_u, offs_u, (size_t)n_users * 4, hipMemcpyDeviceToDevice, stream);
  k_scatter_kg<<<(e_kg + NT - 1) / NT, NT, 0, stream>>>(head, tail, edge_type, cur_e, te_s, e_kg);
  k_scatter_ui<<<(e_ui + NT - 1) / NT, NT, 0, stream>>>(iu, ii, inter_w, cur_u, iw_s, e_ui);

  float* res_e = out;
  float* res_u = out + (size_t)n_ent * 128;
  u16* PC[2] = {PCa, PCb};
  for (int hop = 0; hop < 2; ++hop) {
    const float* base_e = (hop == 0) ? entity_emb : nullptr;
    const float* base_u = (hop == 0) ? user_emb : nullptr;
    k_gemm<<<256, NT, 0, stream>>>(PC[hop], W_Q, PC[hop], n_ent);
    k_entity<<<(n_ent + 3) / 4, NT, 0, stream>>>(PC[hop], offs_e, te_s, rel_emb, base_e,
                                                 hop == 0 ? PC[1] : nullptr, res_e, n_ent);
    k_user<<<(n_users + 3) / 4, NT, 0, stream>>>(PC[hop], iw_s, offs_u, base_u, res_u, n_users);
  }
}

// Round 4
// 761.786 us; speedup vs baseline: 2.1962x; 1.1321x over previous
//
#include <hip/hip_runtime.h>
#include <math.h>

#define NT 256
typedef unsigned short u16;
typedef __attribute__((ext_vector_type(8))) u16 u16x8;
typedef __attribute__((ext_vector_type(4))) u16 u16x4;
typedef __attribute__((ext_vector_type(8))) short bf16x8;
typedef __attribute__((ext_vector_type(4))) float f32x4;

__device__ __forceinline__ float bf2f(u16 h) {
  union { unsigned u; float f; } v;
  v.u = ((unsigned)h) << 16;
  return v.f;
}
__device__ __forceinline__ u16 f2bf(float f) {
  union { float f; unsigned u; } v;
  v.f = f;
  unsigned r = v.u + 0x7FFFu + ((v.u >> 16) & 1u);
  return (u16)(r >> 16);
}

// ---------------- CSR build (combined entity+user) ----------------
__global__ __launch_bounds__(NT) void k_hist(const int* __restrict__ head, int n_kg,
                                             const int* __restrict__ usr, int n_ui,
                                             int* __restrict__ deg, int n_ent) {
  int i = blockIdx.x * NT + threadIdx.x;
  if (i < n_kg) atomicAdd(&deg[head[i]], 1);
  if (i < n_ui) atomicAdd(&deg[n_ent + usr[i]], 1);
}

__global__ __launch_bounds__(NT) void k_scan1(const int* __restrict__ in, int* __restrict__ out,
                                              int* __restrict__ aux, int n) {
  __shared__ int sd[NT];
  int t = threadIdx.x;
  int base = blockIdx.x * (NT * 8) + t * 8;
  int v[8], ex[8];
  int run = 0;
#pragma unroll
  for (int j = 0; j < 8; ++j) {
    v[j] = (base + j < n) ? in[base + j] : 0;
    ex[j] = run;
    run += v[j];
  }
  sd[t] = run;
  __syncthreads();
  for (int off = 1; off < NT; off <<= 1) {
    int x = (t >= off) ? sd[t - off] : 0;
    __syncthreads();
    sd[t] += x;
    __syncthreads();
  }
  int texcl = sd[t] - run;
#pragma unroll
  for (int j = 0; j < 8; ++j)
    if (base + j < n) out[base + j] = texcl + ex[j];
  if (t == NT - 1) aux[blockIdx.x] = sd[NT - 1];
}

__global__ __launch_bounds__(NT) void k_scan2(int* __restrict__ aux, int nb) {
  __shared__ int sd[NT];
  int t = threadIdx.x;
  int v = (t < nb) ? aux[t] : 0;
  sd[t] = v;
  __syncthreads();
  for (int off = 1; off < NT; off <<= 1) {
    int x = (t >= off) ? sd[t - off] : 0;
    __syncthreads();
    sd[t] += x;
    __syncthreads();
  }
  if (t < nb) aux[t] = sd[t] - v;  // exclusive
}

// adds block offsets AND mirrors the result into the cursor array
__global__ __launch_bounds__(NT) void k_scan3(int* __restrict__ out, int* __restrict__ cur,
                                              const int* __restrict__ aux, int n) {
  int base = blockIdx.x * (NT * 8) + threadIdx.x * 8;
  int add = aux[blockIdx.x];
#pragma unroll
  for (int j = 0; j < 8; ++j)
    if (base + j < n) {
      int v = out[base + j] + add;
      out[base + j] = v;
      cur[base + j] = v;
    }
}

// scatter packed payloads into the combined edge buffer
__global__ __launch_bounds__(NT) void k_scatter(
    const int* __restrict__ head, const int* __restrict__ tail, const int* __restrict__ etype, int n_kg,
    const int* __restrict__ usr, const int* __restrict__ item, const float* __restrict__ w, int n_ui,
    int* __restrict__ cursor, int* __restrict__ comb, int n_ent) {
  int i = blockIdx.x * NT + threadIdx.x;
  if (i < n_kg) {
    int p = atomicAdd(&cursor[head[i]], 1);
    comb[p] = tail[i] | ((etype[i] - 1) << 20);
  }
  if (i < n_ui) {
    int p = atomicAdd(&cursor[n_ent + usr[i]], 1);
    int wq = (int)(w[i] * 16383.0f + 0.5f);
    if (wq > 16383) wq = 16383;
    comb[p] = (int)(((unsigned)item[i]) | (((unsigned)wq) << 18));
  }
}

// ---------------- convert fp32 embeddings -> cur-half of PC (bf16) ----------------
__global__ __launch_bounds__(NT) void k_cvt(const float* __restrict__ src, u16* __restrict__ dst, int n_ent) {
  long i = (long)blockIdx.x * NT + threadIdx.x;
  if (i >= (long)n_ent * 32) return;
  long row = i >> 5;
  int c4 = (int)(i & 31) * 4;
  float4 v = *(const float4*)(src + row * 128 + c4);
  u16x4 o = {f2bf(v.x), f2bf(v.y), f2bf(v.z), f2bf(v.w)};
  *(u16x4*)(dst + row * 256 + 128 + c4) = o;
}

// ---------------- MFMA GEMM: P-half(PC) = cur-half(PC) @ W, bf16 in/out ----------------
__global__ __launch_bounds__(NT) void k_gemm(const u16* __restrict__ PCin, const float* __restrict__ W,
                                             u16* __restrict__ PCout, int M) {
  __shared__ u16 WT[128 * 136];  // W^T[n][k]
  for (int i = threadIdx.x; i < 128 * 32; i += NT) {
    int n = i & 127, k4 = (i >> 7) << 2;
    u16x4 o = {f2bf(W[(k4 + 0) * 128 + n]), f2bf(W[(k4 + 1) * 128 + n]),
               f2bf(W[(k4 + 2) * 128 + n]), f2bf(W[(k4 + 3) * 128 + n])};
    *(u16x4*)&WT[n * 136 + k4] = o;
  }
  __syncthreads();
  int lane = threadIdx.x & 63;
  int l15 = lane & 15, l4 = lane >> 4;
  int wave = blockIdx.x * (NT / 64) + (threadIdx.x >> 6);
  int nw = gridDim.x * (NT / 64);
  int ntiles = (M + 15) >> 4;
  for (int tile = wave; tile < ntiles; tile += nw) {
    long row0 = (long)tile * 16;
    long ar = row0 + l15;
    if (ar > (long)M - 1) ar = (long)M - 1;
    const u16* arow = PCin + ar * 256 + 128;  // cur half
    bf16x8 af[4];
#pragma unroll
    for (int kk = 0; kk < 4; ++kk) af[kk] = *(const bf16x8*)(arow + kk * 32 + l4 * 8);
    f32x4 acc[8];
#pragma unroll
    for (int nt = 0; nt < 8; ++nt) acc[nt] = (f32x4){0.f, 0.f, 0.f, 0.f};
#pragma unroll
    for (int kk = 0; kk < 4; ++kk) {
#pragma unroll
      for (int nt = 0; nt < 8; ++nt) {
        bf16x8 bf = *(const bf16x8*)&WT[(nt * 16 + l15) * 136 + kk * 32 + l4 * 8];
        acc[nt] = __builtin_amdgcn_mfma_f32_16x16x32_bf16(af[kk], bf, acc[nt], 0, 0, 0);
      }
    }
#pragma unroll
    for (int nt = 0; nt < 8; ++nt) {
#pragma unroll
      for (int j = 0; j < 4; ++j) {
        long row = row0 + l4 * 4 + j;
        if (row < M) PCout[row * 256 + nt * 16 + l15] = f2bf(acc[nt][j]);
      }
    }
  }
}

// ---------------- entity attention-aggregate + l2norm + residual ----------------
// 16-lane unit per edge (4 units/wave, same segment). Lane owns 8 channels;
// loads both P and cur 16B chunks of its channels. Single-pass exp softmax
// (scores are O(0.1) -- no overflow). 2-deep pipelined gathers.
__global__ __launch_bounds__(NT) void k_entity(
    const u16* __restrict__ PC, const int* __restrict__ offs, const int* __restrict__ comb,
    const float* __restrict__ rel_emb, const float* __restrict__ base,
    u16* __restrict__ nextPC, float* __restrict__ res, int n_ent) {
  __shared__ float rel[9 * 128];
  for (int i = threadIdx.x; i < 9 * 128; i += NT) rel[i] = rel_emb[i];
  __syncthreads();
  int wid = (blockIdx.x * NT + threadIdx.x) >> 6;
  int lane = threadIdx.x & 63;
  if (wid >= n_ent) return;
  int unit = lane >> 4;   // 0..3 : which edge slot
  int cl = lane & 15;     // channel chunk (8 ch); head = cl>>3
  const u16x8* PC8 = (const u16x8*)PC;  // 32 x 16B chunks per entity (16 P + 16 cur)
  u16x8 qh = PC8[(size_t)wid * 32 + cl];
  float q[8];
#pragma unroll
  for (int j = 0; j < 8; ++j) q[j] = bf2f(qh[j]) * 0.125f;  // fold 1/sqrt(64)
  float s = 0.f;
  float a[8] = {0.f, 0.f, 0.f, 0.f, 0.f, 0.f, 0.f, 0.f};
  int beg = offs[wid], end = offs[wid + 1];
  int idx = beg + unit;
  bool act = idx < end;
  unsigned te = act ? (unsigned)comb[idx] : 0u;
  size_t rbase = (size_t)(te & 0xFFFFF) * 32 + cl;
  u16x8 dP = PC8[rbase];
  u16x8 dC = PC8[rbase + 16];
  while (act) {
    // prefetch edge idx+4
    int nidx = idx + 4;
    bool nact = nidx < end;
    unsigned nte = nact ? (unsigned)comb[nidx] : 0u;
    size_t nrb = (size_t)(nte & 0xFFFFF) * 32 + cl;
    u16x8 nP = PC8[nrb];
    u16x8 nC = PC8[nrb + 16];
    // process current
    const float* rp = &rel[(te >> 20) * 128 + cl * 8];
    float4 rA = *(const float4*)rp;
    float4 rB = *(const float4*)(rp + 4);
    float rl[8] = {rA.x, rA.y, rA.z, rA.w, rB.x, rB.y, rB.z, rB.w};
    float pp = 0.f;
#pragma unroll
    for (int j = 0; j < 8; ++j) pp += q[j] * (bf2f(dP[j]) * rl[j]);
    pp += __shfl_xor(pp, 1);
    pp += __shfl_xor(pp, 2);
    pp += __shfl_xor(pp, 4);  // each lane now has its own head's score
    float e = __expf(pp);
    s += e;
#pragma unroll
    for (int j = 0; j < 8; ++j) a[j] = fmaf(bf2f(dC[j]) * rl[j], e, a[j]);
    dP = nP;
    dC = nC;
    te = nte;
    idx = nidx;
    act = nact;
  }
  // merge the 4 units
  s += __shfl_xor(s, 16);
  s += __shfl_xor(s, 32);
#pragma unroll
  for (int j = 0; j < 8; ++j) {
    a[j] += __shfl_xor(a[j], 16);
    a[j] += __shfl_xor(a[j], 32);
  }
  float invs = 1.0f / fmaxf(s, 1e-16f);
  float gv[8];
  float nr = 0.f;
#pragma unroll
  for (int j = 0; j < 8; ++j) {
    gv[j] = a[j] * invs;
    nr += gv[j] * gv[j];
  }
  nr += __shfl_xor(nr, 1);
  nr += __shfl_xor(nr, 2);
  nr += __shfl_xor(nr, 4);
  nr += __shfl_xor(nr, 8);
  float inv = 1.0f / fmaxf(sqrtf(nr), 1e-12f);
#pragma unroll
  for (int j = 0; j < 8; ++j) gv[j] *= inv;
  if (lane < 16) {  // unit 0 owns the writeback
    if (nextPC) {
      u16x8 o;
#pragma unroll
      for (int j = 0; j < 8; ++j) o[j] = f2bf(gv[j]);
      ((u16x8*)nextPC)[(size_t)wid * 32 + 16 + cl] = o;  // cur-half chunk
    }
    size_t o4 = (size_t)wid * 128 + cl * 8;
    const float* bp = base ? (base + o4) : (res + o4);
    float4 r0 = *(const float4*)bp;
    float4 r1 = *(const float4*)(bp + 4);
    r0.x += gv[0]; r0.y += gv[1]; r0.z += gv[2]; r0.w += gv[3];
    r1.x += gv[4]; r1.y += gv[5]; r1.z += gv[6]; r1.w += gv[7];
    *(float4*)(res + o4) = r0;
    *(float4*)(res + o4 + 4) = r1;
  }
}

// ---------------- user aggregate + l2norm + residual ----------------
__global__ __launch_bounds__(NT) void k_user(
    const u16* __restrict__ PC, const int* __restrict__ comb, const int* __restrict__ offs,
    const float* __restrict__ base, float* __restrict__ res, int n_users) {
  int wid = (blockIdx.x * NT + threadIdx.x) >> 6;
  int lane = threadIdx.x & 63;
  if (wid >= n_users) return;
  int unit = lane >> 4;
  int cl = lane & 15;
  const u16x8* PC8 = (const u16x8*)PC;
  float a[8] = {0.f, 0.f, 0.f, 0.f, 0.f, 0.f, 0.f, 0.f};
  int beg = offs[wid], end = offs[wid + 1];
  int idx = beg + unit;
  bool act = idx < end;
  unsigned iw = act ? (unsigned)comb[idx] : 0u;
  u16x8 dC = PC8[(size_t)(iw & 0x3FFFF) * 32 + 16 + cl];
  while (act) {
    int nidx = idx + 4;
    bool nact = nidx < end;
    unsigned niw = nact ? (unsigned)comb[nidx] : 0u;
    u16x8 nC = PC8[(size_t)(niw & 0x3FFFF) * 32 + 16 + cl];
    float ww = (float)(iw >> 18) * (1.0f / 16383.0f);
#pragma unroll
    for (int j = 0; j < 8; ++j) a[j] = fmaf(bf2f(dC[j]), ww, a[j]);
    dC = nC;
    iw = niw;
    idx = nidx;
    act = nact;
  }
#pragma unroll
  for (int j = 0; j < 8; ++j) {
    a[j] += __shfl_xor(a[j], 16);
    a[j] += __shfl_xor(a[j], 32);
  }
  float nr = 0.f;
#pragma unroll
  for (int j = 0; j < 8; ++j) nr += a[j] * a[j];
  nr += __shfl_xor(nr, 1);
  nr += __shfl_xor(nr, 2);
  nr += __shfl_xor(nr, 4);
  nr += __shfl_xor(nr, 8);
  float inv = 1.0f / fmaxf(sqrtf(nr), 1e-12f);
  if (lane < 16) {
    size_t o = (size_t)wid * 128 + cl * 8;
    const float* bp = base ? (base + o) : (res + o);
    float4 r0 = *(const float4*)bp;
    float4 r1 = *(const float4*)(bp + 4);
    r0.x += a[0] * inv; r0.y += a[1] * inv; r0.z += a[2] * inv; r0.w += a[3] * inv;
    r1.x += a[4] * inv; r1.y += a[5] * inv; r1.z += a[6] * inv; r1.w += a[7] * inv;
    *(float4*)(res + o) = r0;
    *(float4*)(res + o + 4) = r1;
  }
}

// ---------------- host ----------------
extern "C" void kernel_launch(void* const* d_in, const int* in_sizes, int n_in,
                              void* d_out, int out_size, void* d_ws, size_t ws_size,
                              hipStream_t stream) {
  const float* user_emb = (const float*)d_in[0];
  const float* entity_emb = (const float*)d_in[1];
  const int* edge_index = (const int*)d_in[2];
  const int* edge_type = (const int*)d_in[3];
  const int* inter_edge = (const int*)d_in[4];
  const float* inter_w = (const float*)d_in[5];
  const float* rel_emb = (const float*)d_in[6];
  const float* W_Q = (const float*)d_in[7];
  float* out = (float*)d_out;

  int n_users = in_sizes[0] / 128;
  int n_ent = in_sizes[1] / 128;
  int e_kg = in_sizes[3];
  int e_ui = in_sizes[5];
  const int* head = edge_index;
  const int* tail = edge_index + e_kg;
  const int* iu = inter_edge;         // users
  const int* ii = inter_edge + e_ui;  // items

  int n_seg = n_ent + n_users;

  // workspace carve
  char* wp = (char*)d_ws;
  auto take = [&](size_t bytes) {
    char* p = wp;
    wp += (bytes + 255) & ~(size_t)255;
    return p;
  };
  u16* PCa = (u16*)take((size_t)n_ent * 256 * 2);
  u16* PCb = (u16*)take((size_t)n_ent * 256 * 2);
  int* deg = (int*)take((size_t)(n_seg + 1) * 4);
  int* offs = (int*)take((size_t)(n_seg + 1) * 4);
  int* cur = (int*)take((size_t)(n_seg + 1) * 4);
  int* comb = (int*)take((size_t)(e_kg + e_ui) * 4);
  int* aux = (int*)take(1024);
  (void)ws_size;
  (void)n_in;
  (void)out_size;

  // cur-half of PCa <- entity_emb (bf16)
  k_cvt<<<(n_ent * 32 + NT - 1) / NT, NT, 0, stream>>>(entity_emb, PCa, n_ent);

  // combined CSR build (shared by both hops)
  hipMemsetAsync(deg, 0, (size_t)(n_seg + 1) * 4, stream);
  int emax = e_kg > e_ui ? e_kg : e_ui;
  k_hist<<<(emax + NT - 1) / NT, NT, 0, stream>>>(head, e_kg, iu, e_ui, deg, n_ent);
  int nscan = n_seg + 1;
  int nb = (nscan + NT * 8 - 1) / (NT * 8);
  k_scan1<<<nb, NT, 0, stream>>>(deg, offs, aux, nscan);
  k_scan2<<<1, NT, 0, stream>>>(aux, nb);
  k_scan3<<<nb, NT, 0, stream>>>(offs, cur, aux, nscan);
  k_scatter<<<(emax + NT - 1) / NT, NT, 0, stream>>>(head, tail, edge_type, e_kg,
                                                     iu, ii, inter_w, e_ui, cur, comb, n_ent);

  float* res_e = out;
  float* res_u = out + (size_t)n_ent * 128;
  const int* offs_u = offs + n_ent;
  u16* PC[2] = {PCa, PCb};
  for (int hop = 0; hop < 2; ++hop) {
    const float* base_e = (hop == 0) ? entity_emb : nullptr;
    const float* base_u = (hop == 0) ? user_emb : nullptr;
    k_gemm<<<256, NT, 0, stream>>>(PC[hop], W_Q, PC[hop], n_ent);
    k_entity<<<(n_ent + 3) / 4, NT, 0, stream>>>(PC[hop], offs, comb, rel_emb, base_e,
                                                 hop == 0 ? PC[1] : nullptr, res_e, n_ent);
    k_user<<<(n_users + 3) / 4, NT, 0, stream>>>(PC[hop], comb, offs_u, base_u, res_u, n_users);
  }
}

// Round 5
// 663.704 us; speedup vs baseline: 2.5208x; 1.1478x over previous
//
#include <hip/hip_runtime.h>
#include <math.h>

#define NT 256
typedef unsigned short u16;
typedef __attribute__((ext_vector_type(8))) u16 u16x8;
typedef __attribute__((ext_vector_type(4))) u16 u16x4;
typedef __attribute__((ext_vector_type(8))) short bf16x8;
typedef __attribute__((ext_vector_type(4))) float f32x4;

__device__ __forceinline__ float bf2f(u16 h) {
  union { unsigned u; float f; } v;
  v.u = ((unsigned)h) << 16;
  return v.f;
}
__device__ __forceinline__ u16 f2bf(float f) {
  union { float f; unsigned u; } v;
  v.f = f;
  unsigned r = v.u + 0x7FFFu + ((v.u >> 16) & 1u);
  return (u16)(r >> 16);
}

// ---------------- CSR build (combined entity+user) ----------------
__global__ __launch_bounds__(NT) void k_hist(const int* __restrict__ head, int n_kg,
                                             const int* __restrict__ usr, int n_ui,
                                             int* __restrict__ deg, int n_ent) {
  int i = blockIdx.x * NT + threadIdx.x;
  if (i < n_kg) atomicAdd(&deg[head[i]], 1);
  if (i < n_ui) atomicAdd(&deg[n_ent + usr[i]], 1);
}

__global__ __launch_bounds__(NT) void k_scan1(const int* __restrict__ in, int* __restrict__ out,
                                              int* __restrict__ aux, int n) {
  __shared__ int sd[NT];
  int t = threadIdx.x;
  int base = blockIdx.x * (NT * 8) + t * 8;
  int v[8], ex[8];
  int run = 0;
#pragma unroll
  for (int j = 0; j < 8; ++j) {
    v[j] = (base + j < n) ? in[base + j] : 0;
    ex[j] = run;
    run += v[j];
  }
  sd[t] = run;
  __syncthreads();
  for (int off = 1; off < NT; off <<= 1) {
    int x = (t >= off) ? sd[t - off] : 0;
    __syncthreads();
    sd[t] += x;
    __syncthreads();
  }
  int texcl = sd[t] - run;
#pragma unroll
  for (int j = 0; j < 8; ++j)
    if (base + j < n) out[base + j] = texcl + ex[j];
  if (t == NT - 1) aux[blockIdx.x] = sd[NT - 1];
}

__global__ __launch_bounds__(NT) void k_scan2(int* __restrict__ aux, int nb) {
  __shared__ int sd[NT];
  int t = threadIdx.x;
  int v = (t < nb) ? aux[t] : 0;
  sd[t] = v;
  __syncthreads();
  for (int off = 1; off < NT; off <<= 1) {
    int x = (t >= off) ? sd[t - off] : 0;
    __syncthreads();
    sd[t] += x;
    __syncthreads();
  }
  if (t < nb) aux[t] = sd[t] - v;  // exclusive
}

// adds block offsets AND mirrors the result into the cursor array
__global__ __launch_bounds__(NT) void k_scan3(int* __restrict__ out, int* __restrict__ cur,
                                              const int* __restrict__ aux, int n) {
  int base = blockIdx.x * (NT * 8) + threadIdx.x * 8;
  int add = aux[blockIdx.x];
#pragma unroll
  for (int j = 0; j < 8; ++j)
    if (base + j < n) {
      int v = out[base + j] + add;
      out[base + j] = v;
      cur[base + j] = v;
    }
}

// scatter packed payloads into the combined edge buffer
__global__ __launch_bounds__(NT) void k_scatter(
    const int* __restrict__ head, const int* __restrict__ tail, const int* __restrict__ etype, int n_kg,
    const int* __restrict__ usr, const int* __restrict__ item, const float* __restrict__ w, int n_ui,
    int* __restrict__ cursor, int* __restrict__ comb, int n_ent) {
  int i = blockIdx.x * NT + threadIdx.x;
  if (i < n_kg) {
    int p = atomicAdd(&cursor[head[i]], 1);
    comb[p] = tail[i] | ((etype[i] - 1) << 20);
  }
  if (i < n_ui) {
    int p = atomicAdd(&cursor[n_ent + usr[i]], 1);
    int wq = (int)(w[i] * 16383.0f + 0.5f);
    if (wq > 16383) wq = 16383;
    comb[p] = (int)(((unsigned)item[i]) | (((unsigned)wq) << 18));
  }
}

// ---------------- convert fp32 embeddings -> cur-half of PC (bf16) ----------------
__global__ __launch_bounds__(NT) void k_cvt(const float* __restrict__ src, u16* __restrict__ dst, int n_ent) {
  long i = (long)blockIdx.x * NT + threadIdx.x;
  if (i >= (long)n_ent * 32) return;
  long row = i >> 5;
  int c4 = (int)(i & 31) * 4;
  float4 v = *(const float4*)(src + row * 128 + c4);
  u16x4 o = {f2bf(v.x), f2bf(v.y), f2bf(v.z), f2bf(v.w)};
  *(u16x4*)(dst + row * 256 + 128 + c4) = o;
}

// ---------------- MFMA GEMM: P-half(PC) = cur-half(PC) @ W, bf16 in/out ----------------
__global__ __launch_bounds__(NT) void k_gemm(const u16* __restrict__ PCin, const float* __restrict__ W,
                                             u16* __restrict__ PCout, int M) {
  __shared__ u16 WT[128 * 136];  // W^T[n][k]
  for (int i = threadIdx.x; i < 128 * 32; i += NT) {
    int n = i & 127, k4 = (i >> 7) << 2;
    u16x4 o = {f2bf(W[(k4 + 0) * 128 + n]), f2bf(W[(k4 + 1) * 128 + n]),
               f2bf(W[(k4 + 2) * 128 + n]), f2bf(W[(k4 + 3) * 128 + n])};
    *(u16x4*)&WT[n * 136 + k4] = o;
  }
  __syncthreads();
  int lane = threadIdx.x & 63;
  int l15 = lane & 15, l4 = lane >> 4;
  int wave = blockIdx.x * (NT / 64) + (threadIdx.x >> 6);
  int nw = gridDim.x * (NT / 64);
  int ntiles = (M + 15) >> 4;
  for (int tile = wave; tile < ntiles; tile += nw) {
    long row0 = (long)tile * 16;
    long ar = row0 + l15;
    if (ar > (long)M - 1) ar = (long)M - 1;
    const u16* arow = PCin + ar * 256 + 128;  // cur half
    bf16x8 af[4];
#pragma unroll
    for (int kk = 0; kk < 4; ++kk) af[kk] = *(const bf16x8*)(arow + kk * 32 + l4 * 8);
    f32x4 acc[8];
#pragma unroll
    for (int nt = 0; nt < 8; ++nt) acc[nt] = (f32x4){0.f, 0.f, 0.f, 0.f};
#pragma unroll
    for (int kk = 0; kk < 4; ++kk) {
#pragma unroll
      for (int nt = 0; nt < 8; ++nt) {
        bf16x8 bf = *(const bf16x8*)&WT[(nt * 16 + l15) * 136 + kk * 32 + l4 * 8];
        acc[nt] = __builtin_amdgcn_mfma_f32_16x16x32_bf16(af[kk], bf, acc[nt], 0, 0, 0);
      }
    }
#pragma unroll
    for (int nt = 0; nt < 8; ++nt) {
#pragma unroll
      for (int j = 0; j < 4; ++j) {
        long row = row0 + l4 * 4 + j;
        if (row < M) PCout[row * 256 + nt * 16 + l15] = f2bf(acc[nt][j]);
      }
    }
  }
}

// ---------------- fused segment aggregate (entity attention + user) ----------------
// One 16-lane unit per segment; 4 segments per wave. Entity segments do
// single-pass exp softmax attention; user segments do weighted sums. Epilogue
// (l2norm + residual + nextPC) is fully lane-parallel per unit.
__global__ __launch_bounds__(NT) void k_agg(
    const u16* __restrict__ PC, const int* __restrict__ offs, const int* __restrict__ comb,
    const float* __restrict__ rel_emb, const float* __restrict__ base_e,
    const float* __restrict__ base_u, u16* __restrict__ nextPC,
    float* __restrict__ res_e, float* __restrict__ res_u, int n_ent, int n_seg) {
  __shared__ float rel[9 * 128];
  for (int i = threadIdx.x; i < 9 * 128; i += NT) rel[i] = rel_emb[i];
  __syncthreads();
  int lane = threadIdx.x & 63;
  int unit = lane >> 4;  // 0..3: which segment of this wave
  int cl = lane & 15;    // channel chunk (8 ch); head = cl>>3
  int sseg = (((blockIdx.x * NT + threadIdx.x) >> 6) << 2) + unit;
  if (sseg >= n_seg) return;
  const u16x8* PC8 = (const u16x8*)PC;  // 32 x 16B chunks per entity (16 P + 16 cur)
  int beg = offs[sseg], end = offs[sseg + 1];

  if (sseg < n_ent) {
    // ---- entity attention path ----
    u16x8 qh = PC8[(size_t)sseg * 32 + cl];
    float q[8];
#pragma unroll
    for (int j = 0; j < 8; ++j) q[j] = bf2f(qh[j]) * 0.125f;  // fold 1/sqrt(64)
    float s = 0.f;
    float a[8] = {0.f, 0.f, 0.f, 0.f, 0.f, 0.f, 0.f, 0.f};
    int idx = beg;
    bool act = idx < end;
    unsigned te = act ? (unsigned)comb[idx] : 0u;
    size_t rb = (size_t)(te & 0xFFFFF) * 32 + cl;
    u16x8 dP = PC8[rb];
    u16x8 dC = PC8[rb + 16];
    while (act) {
      int nidx = idx + 1;
      bool nact = nidx < end;
      unsigned nte = nact ? (unsigned)comb[nidx] : 0u;
      size_t nrb = (size_t)(nte & 0xFFFFF) * 32 + cl;
      u16x8 nP = PC8[nrb];
      u16x8 nC = PC8[nrb + 16];
      const float* rp = &rel[(te >> 20) * 128 + cl * 8];
      float4 rA = *(const float4*)rp;
      float4 rB = *(const float4*)(rp + 4);
      float rl[8] = {rA.x, rA.y, rA.z, rA.w, rB.x, rB.y, rB.z, rB.w};
      float pp = 0.f;
#pragma unroll
      for (int j = 0; j < 8; ++j) pp += q[j] * (bf2f(dP[j]) * rl[j]);
      pp += __shfl_xor(pp, 1);
      pp += __shfl_xor(pp, 2);
      pp += __shfl_xor(pp, 4);  // per-head score, resident on its own lanes
      float e = __expf(pp);
      s += e;
#pragma unroll
      for (int j = 0; j < 8; ++j) a[j] = fmaf(bf2f(dC[j]) * rl[j], e, a[j]);
      dP = nP;
      dC = nC;
      te = nte;
      idx = nidx;
      act = nact;
    }
    s += __shfl_xor(s, 8);  // heads share the unit; denom differs per head? NO --
    s -= __shfl_xor(s, 8);  // undo: keep per-head denom (see note below)
    float invs = 1.0f / fmaxf(s, 1e-16f);
    float gv[8];
    float nr = 0.f;
#pragma unroll
    for (int j = 0; j < 8; ++j) {
      gv[j] = a[j] * invs;
      nr += gv[j] * gv[j];
    }
    nr += __shfl_xor(nr, 1);
    nr += __shfl_xor(nr, 2);
    nr += __shfl_xor(nr, 4);
    nr += __shfl_xor(nr, 8);  // norm spans both heads (full 128-ch row)
    float inv = 1.0f / fmaxf(sqrtf(nr), 1e-12f);
#pragma unroll
    for (int j = 0; j < 8; ++j) gv[j] *= inv;
    if (nextPC) {
      u16x8 o;
#pragma unroll
      for (int j = 0; j < 8; ++j) o[j] = f2bf(gv[j]);
      ((u16x8*)nextPC)[(size_t)sseg * 32 + 16 + cl] = o;  // cur-half chunk
    }
    size_t o4 = (size_t)sseg * 128 + cl * 8;
    const float* bp = base_e ? (base_e + o4) : (res_e + o4);
    float4 r0 = *(const float4*)bp;
    float4 r1 = *(const float4*)(bp + 4);
    r0.x += gv[0]; r0.y += gv[1]; r0.z += gv[2]; r0.w += gv[3];
    r1.x += gv[4]; r1.y += gv[5]; r1.z += gv[6]; r1.w += gv[7];
    *(float4*)(res_e + o4) = r0;
    *(float4*)(res_e + o4 + 4) = r1;
  } else {
    // ---- user aggregate path ----
    int u = sseg - n_ent;
    float a[8] = {0.f, 0.f, 0.f, 0.f, 0.f, 0.f, 0.f, 0.f};
    int idx = beg;
    bool act = idx < end;
    unsigned iw = act ? (unsigned)comb[idx] : 0u;
    u16x8 dC = PC8[(size_t)(iw & 0x3FFFF) * 32 + 16 + cl];
    while (act) {
      int nidx = idx + 1;
      bool nact = nidx < end;
      unsigned niw = nact ? (unsigned)comb[nidx] : 0u;
      u16x8 nC = PC8[(size_t)(niw & 0x3FFFF) * 32 + 16 + cl];
      float ww = (float)(iw >> 18) * (1.0f / 16383.0f);
#pragma unroll
      for (int j = 0; j < 8; ++j) a[j] = fmaf(bf2f(dC[j]), ww, a[j]);
      dC = nC;
      iw = niw;
      idx = nidx;
      act = nact;
    }
    float nr = 0.f;
#pragma unroll
    for (int j = 0; j < 8; ++j) nr += a[j] * a[j];
    nr += __shfl_xor(nr, 1);
    nr += __shfl_xor(nr, 2);
    nr += __shfl_xor(nr, 4);
    nr += __shfl_xor(nr, 8);
    float inv = 1.0f / fmaxf(sqrtf(nr), 1e-12f);
    size_t o = (size_t)u * 128 + cl * 8;
    const float* bp = base_u ? (base_u + o) : (res_u + o);
    float4 r0 = *(const float4*)bp;
    float4 r1 = *(const float4*)(bp + 4);
    r0.x += a[0] * inv; r0.y += a[1] * inv; r0.z += a[2] * inv; r0.w += a[3] * inv;
    r1.x += a[4] * inv; r1.y += a[5] * inv; r1.z += a[6] * inv; r1.w += a[7] * inv;
    *(float4*)(res_u + o) = r0;
    *(float4*)(res_u + o + 4) = r1;
  }
}

// ---------------- host ----------------
extern "C" void kernel_launch(void* const* d_in, const int* in_sizes, int n_in,
                              void* d_out, int out_size, void* d_ws, size_t ws_size,
                              hipStream_t stream) {
  const float* user_emb = (const float*)d_in[0];
  const float* entity_emb = (const float*)d_in[1];
  const int* edge_index = (const int*)d_in[2];
  const int* edge_type = (const int*)d_in[3];
  const int* inter_edge = (const int*)d_in[4];
  const float* inter_w = (const float*)d_in[5];
  const float* rel_emb = (const float*)d_in[6];
  const float* W_Q = (const float*)d_in[7];
  float* out = (float*)d_out;

  int n_users = in_sizes[0] / 128;
  int n_ent = in_sizes[1] / 128;
  int e_kg = in_sizes[3];
  int e_ui = in_sizes[5];
  const int* head = edge_index;
  const int* tail = edge_index + e_kg;
  const int* iu = inter_edge;         // users
  const int* ii = inter_edge + e_ui;  // items

  int n_seg = n_ent + n_users;

  // workspace carve
  char* wp = (char*)d_ws;
  auto take = [&](size_t bytes) {
    char* p = wp;
    wp += (bytes + 255) & ~(size_t)255;
    return p;
  };
  u16* PCa = (u16*)take((size_t)n_ent * 256 * 2);
  u16* PCb = (u16*)take((size_t)n_ent * 256 * 2);
  int* deg = (int*)take((size_t)(n_seg + 1) * 4);
  int* offs = (int*)take((size_t)(n_seg + 1) * 4);
  int* cur = (int*)take((size_t)(n_seg + 1) * 4);
  int* comb = (int*)take((size_t)(e_kg + e_ui) * 4);
  int* aux = (int*)take(1024);
  (void)ws_size;
  (void)n_in;
  (void)out_size;

  // cur-half of PCa <- entity_emb (bf16)
  k_cvt<<<(n_ent * 32 + NT - 1) / NT, NT, 0, stream>>>(entity_emb, PCa, n_ent);

  // combined CSR build (shared by both hops)
  hipMemsetAsync(deg, 0, (size_t)(n_seg + 1) * 4, stream);
  int emax = e_kg > e_ui ? e_kg : e_ui;
  k_hist<<<(emax + NT - 1) / NT, NT, 0, stream>>>(head, e_kg, iu, e_ui, deg, n_ent);
  int nscan = n_seg + 1;
  int nb = (nscan + NT * 8 - 1) / (NT * 8);
  k_scan1<<<nb, NT, 0, stream>>>(deg, offs, aux, nscan);
  k_scan2<<<1, NT, 0, stream>>>(aux, nb);
  k_scan3<<<nb, NT, 0, stream>>>(offs, cur, aux, nscan);
  k_scatter<<<(emax + NT - 1) / NT, NT, 0, stream>>>(head, tail, edge_type, e_kg,
                                                     iu, ii, inter_w, e_ui, cur, comb, n_ent);

  float* res_e = out;
  float* res_u = out + (size_t)n_ent * 128;
  u16* PC[2] = {PCa, PCb};
  int agg_blocks = (n_seg + 15) / 16;  // 16 segments per 256-thread block
  for (int hop = 0; hop < 2; ++hop) {
    const float* base_e = (hop == 0) ? entity_emb : nullptr;
    const float* base_u = (hop == 0) ? user_emb : nullptr;
    k_gemm<<<256, NT, 0, stream>>>(PC[hop], W_Q, PC[hop], n_ent);
    k_agg<<<agg_blocks, NT, 0, stream>>>(PC[hop], offs, comb, rel_emb, base_e, base_u,
                                         hop == 0 ? PC[1] : nullptr, res_e, res_u,
                                         n_ent, n_seg);
  }
}

// Round 6
// 653.602 us; speedup vs baseline: 2.5597x; 1.0155x over previous
//
#include <hip/hip_runtime.h>
#include <math.h>

#define NT 256
typedef unsigned short u16;
typedef __attribute__((ext_vector_type(8))) u16 u16x8;
typedef __attribute__((ext_vector_type(4))) u16 u16x4;
typedef __attribute__((ext_vector_type(8))) short bf16x8;
typedef __attribute__((ext_vector_type(4))) float f32x4;

__device__ __forceinline__ float bf2f(u16 h) {
  union { unsigned u; float f; } v;
  v.u = ((unsigned)h) << 16;
  return v.f;
}
__device__ __forceinline__ u16 f2bf(float f) {
  union { float f; unsigned u; } v;
  v.f = f;
  unsigned r = v.u + 0x7FFFu + ((v.u >> 16) & 1u);
  return (u16)(r >> 16);
}

// ---------------- CSR build (combined entity+user) ----------------
__global__ __launch_bounds__(NT) void k_hist(const int* __restrict__ head, int n_kg,
                                             const int* __restrict__ usr, int n_ui,
                                             int* __restrict__ deg, int n_ent) {
  int i = blockIdx.x * NT + threadIdx.x;
  if (i < n_kg) atomicAdd(&deg[head[i]], 1);
  if (i < n_ui) atomicAdd(&deg[n_ent + usr[i]], 1);
}

__global__ __launch_bounds__(NT) void k_scan1(const int* __restrict__ in, int* __restrict__ out,
                                              int* __restrict__ aux, int n) {
  __shared__ int sd[NT];
  int t = threadIdx.x;
  int base = blockIdx.x * (NT * 8) + t * 8;
  int v[8], ex[8];
  int run = 0;
#pragma unroll
  for (int j = 0; j < 8; ++j) {
    v[j] = (base + j < n) ? in[base + j] : 0;
    ex[j] = run;
    run += v[j];
  }
  sd[t] = run;
  __syncthreads();
  for (int off = 1; off < NT; off <<= 1) {
    int x = (t >= off) ? sd[t - off] : 0;
    __syncthreads();
    sd[t] += x;
    __syncthreads();
  }
  int texcl = sd[t] - run;
#pragma unroll
  for (int j = 0; j < 8; ++j)
    if (base + j < n) out[base + j] = texcl + ex[j];
  if (t == NT - 1) aux[blockIdx.x] = sd[NT - 1];
}

__global__ __launch_bounds__(NT) void k_scan2(int* __restrict__ aux, int nb) {
  __shared__ int sd[NT];
  int t = threadIdx.x;
  int v = (t < nb) ? aux[t] : 0;
  sd[t] = v;
  __syncthreads();
  for (int off = 1; off < NT; off <<= 1) {
    int x = (t >= off) ? sd[t - off] : 0;
    __syncthreads();
    sd[t] += x;
    __syncthreads();
  }
  if (t < nb) aux[t] = sd[t] - v;  // exclusive
}

// adds block offsets AND mirrors the result into the cursor array
__global__ __launch_bounds__(NT) void k_scan3(int* __restrict__ out, int* __restrict__ cur,
                                              const int* __restrict__ aux, int n) {
  int base = blockIdx.x * (NT * 8) + threadIdx.x * 8;
  int add = aux[blockIdx.x];
#pragma unroll
  for (int j = 0; j < 8; ++j)
    if (base + j < n) {
      int v = out[base + j] + add;
      out[base + j] = v;
      cur[base + j] = v;
    }
}

// scatter packed payloads into the combined edge buffer
__global__ __launch_bounds__(NT) void k_scatter(
    const int* __restrict__ head, const int* __restrict__ tail, const int* __restrict__ etype, int n_kg,
    const int* __restrict__ usr, const int* __restrict__ item, const float* __restrict__ w, int n_ui,
    int* __restrict__ cursor, int* __restrict__ comb, int n_ent) {
  int i = blockIdx.x * NT + threadIdx.x;
  if (i < n_kg) {
    int p = atomicAdd(&cursor[head[i]], 1);
    comb[p] = tail[i] | ((etype[i] - 1) << 20);
  }
  if (i < n_ui) {
    int p = atomicAdd(&cursor[n_ent + usr[i]], 1);
    int wq = (int)(w[i] * 16383.0f + 0.5f);
    if (wq > 16383) wq = 16383;
    comb[p] = (int)(((unsigned)item[i]) | (((unsigned)wq) << 18));
  }
}

// ---------------- degree-bucket sort of segments (type-pure, descending) ----------------
// bin = (entity? 0 : 64) + 63 - min(deg,63); perm = segments in bin order.
__device__ __forceinline__ int seg_bin(int deg, int i, int n_ent) {
  int d = deg < 63 ? deg : 63;
  return (i < n_ent ? 0 : 64) + 63 - d;
}

__global__ __launch_bounds__(NT) void k_bhist(const int* __restrict__ deg, int* __restrict__ bh,
                                              int n_ent, int n_seg) {
  __shared__ int lh[128];
  if (threadIdx.x < 128) lh[threadIdx.x] = 0;
  __syncthreads();
  for (int i = blockIdx.x * NT + threadIdx.x; i < n_seg; i += gridDim.x * NT)
    atomicAdd(&lh[seg_bin(deg[i], i, n_ent)], 1);
  __syncthreads();
  if (threadIdx.x < 128) atomicAdd(&bh[threadIdx.x], lh[threadIdx.x]);
}

__global__ __launch_bounds__(128) void k_bscan(int* __restrict__ bh) {
  __shared__ int sd[128];
  int t = threadIdx.x;
  int v = bh[t];
  sd[t] = v;
  __syncthreads();
  for (int off = 1; off < 128; off <<= 1) {
    int x = (t >= off) ? sd[t - off] : 0;
    __syncthreads();
    sd[t] += x;
    __syncthreads();
  }
  bh[t] = sd[t] - v;  // exclusive
}

__global__ __launch_bounds__(NT) void k_bscatter(const int* __restrict__ deg, int* __restrict__ bcur,
                                                 int* __restrict__ perm, int n_ent, int n_seg) {
  __shared__ int lh[128], lbase[128];
  if (threadIdx.x < 128) lh[threadIdx.x] = 0;
  __syncthreads();
  int start = blockIdx.x * NT + threadIdx.x, stride = gridDim.x * NT;
  for (int i = start; i < n_seg; i += stride)
    atomicAdd(&lh[seg_bin(deg[i], i, n_ent)], 1);
  __syncthreads();
  if (threadIdx.x < 128) {
    lbase[threadIdx.x] = atomicAdd(&bcur[threadIdx.x], lh[threadIdx.x]);
    lh[threadIdx.x] = 0;
  }
  __syncthreads();
  for (int i = start; i < n_seg; i += stride) {
    int b = seg_bin(deg[i], i, n_ent);
    int off = atomicAdd(&lh[b], 1);
    perm[lbase[b] + off] = i;
  }
}

// ---------------- MFMA GEMM: P-half(PC) = A @ W, bf16 out ----------------
// If A32 != nullptr: A read from fp32 (hop 0), and the bf16 cur-half of PCout
// is written too (fused convert). Else A = cur-half of PCin.
__global__ __launch_bounds__(NT) void k_gemm(const u16* __restrict__ PCin, const float* __restrict__ A32,
                                             const float* __restrict__ W, u16* __restrict__ PCout, int M) {
  __shared__ u16 WT[128 * 136];  // W^T[n][k]
  for (int i = threadIdx.x; i < 128 * 32; i += NT) {
    int n = i & 127, k4 = (i >> 7) << 2;
    u16x4 o = {f2bf(W[(k4 + 0) * 128 + n]), f2bf(W[(k4 + 1) * 128 + n]),
               f2bf(W[(k4 + 2) * 128 + n]), f2bf(W[(k4 + 3) * 128 + n])};
    *(u16x4*)&WT[n * 136 + k4] = o;
  }
  __syncthreads();
  int lane = threadIdx.x & 63;
  int l15 = lane & 15, l4 = lane >> 4;
  int wave = blockIdx.x * (NT / 64) + (threadIdx.x >> 6);
  int nw = gridDim.x * (NT / 64);
  int ntiles = (M + 15) >> 4;
  for (int tile = wave; tile < ntiles; tile += nw) {
    long row0 = (long)tile * 16;
    long myrow = row0 + l15;
    bool rowok = myrow < M;
    long ar = rowok ? myrow : (long)(M - 1);
    bf16x8 af[4];
    if (A32) {
      const float* arow = A32 + ar * 128;
#pragma unroll
      for (int kk = 0; kk < 4; ++kk) {
        const float* p = arow + kk * 32 + l4 * 8;
        float4 f0 = *(const float4*)p;
        float4 f1 = *(const float4*)(p + 4);
        u16x8 t = {f2bf(f0.x), f2bf(f0.y), f2bf(f0.z), f2bf(f0.w),
                   f2bf(f1.x), f2bf(f1.y), f2bf(f1.z), f2bf(f1.w)};
        af[kk] = *(bf16x8*)&t;
        if (rowok) *(u16x8*)&PCout[(size_t)ar * 256 + 128 + kk * 32 + l4 * 8] = t;
      }
    } else {
      const u16* arow = PCin + ar * 256 + 128;  // cur half
#pragma unroll
      for (int kk = 0; kk < 4; ++kk) af[kk] = *(const bf16x8*)(arow + kk * 32 + l4 * 8);
    }
    f32x4 acc[8];
#pragma unroll
    for (int nt = 0; nt < 8; ++nt) acc[nt] = (f32x4){0.f, 0.f, 0.f, 0.f};
#pragma unroll
    for (int kk = 0; kk < 4; ++kk) {
#pragma unroll
      for (int nt = 0; nt < 8; ++nt) {
        bf16x8 bf = *(const bf16x8*)&WT[(nt * 16 + l15) * 136 + kk * 32 + l4 * 8];
        acc[nt] = __builtin_amdgcn_mfma_f32_16x16x32_bf16(af[kk], bf, acc[nt], 0, 0, 0);
      }
    }
#pragma unroll
    for (int nt = 0; nt < 8; ++nt) {
#pragma unroll
      for (int j = 0; j < 4; ++j) {
        long row = row0 + l4 * 4 + j;
        if (row < M) PCout[row * 256 + nt * 16 + l15] = f2bf(acc[nt][j]);
      }
    }
  }
}

// ---------------- fused segment aggregate (entity attention + user) ----------------
// One 16-lane unit per segment; 4 degree-matched segments per wave via perm[].
// Entities: single-pass exp softmax attention; hop0 writes only nextPC (bf16),
// hop1 writes res = base + g0(from PC cur-half) + g1. Users: weighted sum,
// res RMW. Distance-2 branch-free payload pipeline.
__global__ __launch_bounds__(NT) void k_agg(
    const u16* __restrict__ PC, const int* __restrict__ offs, const int* __restrict__ comb,
    const int* __restrict__ perm, const float* __restrict__ rel_emb,
    const float* __restrict__ base_e, const float* __restrict__ base_u,
    u16* __restrict__ nextPC, float* __restrict__ res_e, float* __restrict__ res_u,
    int n_ent, int n_seg, int hop0) {
  __shared__ float rel[9 * 128];
  for (int i = threadIdx.x; i < 9 * 128; i += NT) rel[i] = rel_emb[i];
  __syncthreads();
  int lane = threadIdx.x & 63;
  int unit = lane >> 4;  // 0..3: which segment of this wave
  int cl = lane & 15;    // channel chunk (8 ch); head = cl>>3
  int vid = (((blockIdx.x * NT + threadIdx.x) >> 6) << 2) + unit;
  if (vid >= n_seg) return;
  int sseg = perm[vid];
  const u16x8* PC8 = (const u16x8*)PC;  // 32 x 16B chunks per entity (16 P + 16 cur)
  int beg = offs[sseg], end = offs[sseg + 1];
  int cnt = end - beg;

  if (sseg < n_ent) {
    // ---- entity attention path ----
    u16x8 qh = PC8[(size_t)sseg * 32 + cl];
    float q[8];
#pragma unroll
    for (int j = 0; j < 8; ++j) q[j] = bf2f(qh[j]) * 0.125f;  // fold 1/sqrt(64)
    float s = 0.f;
    float a[8] = {0.f, 0.f, 0.f, 0.f, 0.f, 0.f, 0.f, 0.f};
    unsigned te0 = 0, te1 = 0;
    u16x8 P0 = {}, C0 = {}, P1 = {}, C1 = {};
    if (cnt > 0) {
      te0 = (unsigned)comb[beg];
      te1 = (unsigned)comb[beg + (cnt > 1 ? 1 : 0)];
      size_t r0 = (size_t)(te0 & 0xFFFFF) * 32 + cl;
      size_t r1 = (size_t)(te1 & 0xFFFFF) * 32 + cl;
      P0 = PC8[r0]; C0 = PC8[r0 + 16];
      P1 = PC8[r1]; C1 = PC8[r1 + 16];
    }
    for (int i = 0; i < cnt; ++i) {
      unsigned te2 = (unsigned)comb[beg + (i + 2 < cnt ? i + 2 : cnt - 1)];
      size_t r2 = (size_t)(te2 & 0xFFFFF) * 32 + cl;
      u16x8 P2 = PC8[r2], C2 = PC8[r2 + 16];
      const float* rp = &rel[(te0 >> 20) * 128 + cl * 8];
      float4 rA = *(const float4*)rp;
      float4 rB = *(const float4*)(rp + 4);
      float rl[8] = {rA.x, rA.y, rA.z, rA.w, rB.x, rB.y, rB.z, rB.w};
      float pp = 0.f;
#pragma unroll
      for (int j = 0; j < 8; ++j) pp += q[j] * (bf2f(P0[j]) * rl[j]);
      pp += __shfl_xor(pp, 1);
      pp += __shfl_xor(pp, 2);
      pp += __shfl_xor(pp, 4);  // per-head score on its own lanes
      float e = __expf(pp);
      s += e;
#pragma unroll
      for (int j = 0; j < 8; ++j) a[j] = fmaf(bf2f(C0[j]) * rl[j], e, a[j]);
      te0 = te1; P0 = P1; C0 = C1;
      te1 = te2; P1 = P2; C1 = C2;
    }
    float invs = 1.0f / fmaxf(s, 1e-16f);
    float gv[8];
    float nr = 0.f;
#pragma unroll
    for (int j = 0; j < 8; ++j) {
      gv[j] = a[j] * invs;
      nr += gv[j] * gv[j];
    }
    nr += __shfl_xor(nr, 1);
    nr += __shfl_xor(nr, 2);
    nr += __shfl_xor(nr, 4);
    nr += __shfl_xor(nr, 8);  // norm spans both heads
    float inv = 1.0f / fmaxf(sqrtf(nr), 1e-12f);
#pragma unroll
    for (int j = 0; j < 8; ++j) gv[j] *= inv;
    if (hop0) {
      u16x8 o;
#pragma unroll
      for (int j = 0; j < 8; ++j) o[j] = f2bf(gv[j]);
      ((u16x8*)nextPC)[(size_t)sseg * 32 + 16 + cl] = o;  // cur-half of next hop
    } else {
      u16x8 g0 = PC8[(size_t)sseg * 32 + 16 + cl];  // hop0 result (cur-half)
      size_t o4 = (size_t)sseg * 128 + (size_t)cl * 8;
      float4 b0 = *(const float4*)(base_e + o4);
      float4 b1 = *(const float4*)(base_e + o4 + 4);
      float4 w0 = {b0.x + bf2f(g0[0]) + gv[0], b0.y + bf2f(g0[1]) + gv[1],
                   b0.z + bf2f(g0[2]) + gv[2], b0.w + bf2f(g0[3]) + gv[3]};
      float4 w1 = {b1.x + bf2f(g0[4]) + gv[4], b1.y + bf2f(g0[5]) + gv[5],
                   b1.z + bf2f(g0[6]) + gv[6], b1.w + bf2f(g0[7]) + gv[7]};
      *(float4*)(res_e + o4) = w0;
      *(float4*)(res_e + o4 + 4) = w1;
    }
  } else {
    // ---- user aggregate path ----
    int u = sseg - n_ent;
    float a[8] = {0.f, 0.f, 0.f, 0.f, 0.f, 0.f, 0.f, 0.f};
    unsigned iw0 = 0, iw1 = 0;
    u16x8 C0 = {}, C1 = {};
    if (cnt > 0) {
      iw0 = (unsigned)comb[beg];
      iw1 = (unsigned)comb[beg + (cnt > 1 ? 1 : 0)];
      C0 = PC8[(size_t)(iw0 & 0x3FFFF) * 32 + 16 + cl];
      C1 = PC8[(size_t)(iw1 & 0x3FFFF) * 32 + 16 + cl];
    }
    for (int i = 0; i < cnt; ++i) {
      unsigned iw2 = (unsigned)comb[beg + (i + 2 < cnt ? i + 2 : cnt - 1)];
      u16x8 C2 = PC8[(size_t)(iw2 & 0x3FFFF) * 32 + 16 + cl];
      float ww = (float)(iw0 >> 18) * (1.0f / 16383.0f);
#pragma unroll
      for (int j = 0; j < 8; ++j) a[j] = fmaf(bf2f(C0[j]), ww, a[j]);
      iw0 = iw1; C0 = C1;
      iw1 = iw2; C1 = C2;
    }
    float nr = 0.f;
#pragma unroll
    for (int j = 0; j < 8; ++j) nr += a[j] * a[j];
    nr += __shfl_xor(nr, 1);
    nr += __shfl_xor(nr, 2);
    nr += __shfl_xor(nr, 4);
    nr += __shfl_xor(nr, 8);
    float inv = 1.0f / fmaxf(sqrtf(nr), 1e-12f);
    size_t o = (size_t)u * 128 + (size_t)cl * 8;
    const float* bp = hop0 ? (base_u + o) : (res_u + o);
    float4 r0 = *(const float4*)bp;
    float4 r1 = *(const float4*)(bp + 4);
    r0.x += a[0] * inv; r0.y += a[1] * inv; r0.z += a[2] * inv; r0.w += a[3] * inv;
    r1.x += a[4] * inv; r1.y += a[5] * inv; r1.z += a[6] * inv; r1.w += a[7] * inv;
    *(float4*)(res_u + o) = r0;
    *(float4*)(res_u + o + 4) = r1;
  }
}

// ---------------- host ----------------
extern "C" void kernel_launch(void* const* d_in, const int* in_sizes, int n_in,
                              void* d_out, int out_size, void* d_ws, size_t ws_size,
                              hipStream_t stream) {
  const float* user_emb = (const float*)d_in[0];
  const float* entity_emb = (const float*)d_in[1];
  const int* edge_index = (const int*)d_in[2];
  const int* edge_type = (const int*)d_in[3];
  const int* inter_edge = (const int*)d_in[4];
  const float* inter_w = (const float*)d_in[5];
  const float* rel_emb = (const float*)d_in[6];
  const float* W_Q = (const float*)d_in[7];
  float* out = (float*)d_out;

  int n_users = in_sizes[0] / 128;
  int n_ent = in_sizes[1] / 128;
  int e_kg = in_sizes[3];
  int e_ui = in_sizes[5];
  const int* head = edge_index;
  const int* tail = edge_index + e_kg;
  const int* iu = inter_edge;         // users
  const int* ii = inter_edge + e_ui;  // items

  int n_seg = n_ent + n_users;

  // workspace carve
  char* wp = (char*)d_ws;
  auto take = [&](size_t bytes) {
    char* p = wp;
    wp += (bytes + 255) & ~(size_t)255;
    return p;
  };
  u16* PCa = (u16*)take((size_t)n_ent * 256 * 2);
  u16* PCb = (u16*)take((size_t)n_ent * 256 * 2);
  int* deg = (int*)take((size_t)(n_seg + 1) * 4);
  int* offs = (int*)take((size_t)(n_seg + 1) * 4);
  int* cur = (int*)take((size_t)(n_seg + 1) * 4);
  int* comb = (int*)take((size_t)(e_kg + e_ui) * 4);
  int* perm = (int*)take((size_t)n_seg * 4);
  int* bh = (int*)take(512);
  int* aux = (int*)take(1024);
  (void)ws_size;
  (void)n_in;
  (void)out_size;

  // combined CSR build (shared by both hops)
  hipMemsetAsync(deg, 0, (size_t)(n_seg + 1) * 4, stream);
  hipMemsetAsync(bh, 0, 512, stream);
  int emax = e_kg > e_ui ? e_kg : e_ui;
  k_hist<<<(emax + NT - 1) / NT, NT, 0, stream>>>(head, e_kg, iu, e_ui, deg, n_ent);
  int nscan = n_seg + 1;
  int nb = (nscan + NT * 8 - 1) / (NT * 8);
  k_scan1<<<nb, NT, 0, stream>>>(deg, offs, aux, nscan);
  k_scan2<<<1, NT, 0, stream>>>(aux, nb);
  k_scan3<<<nb, NT, 0, stream>>>(offs, cur, aux, nscan);
  k_scatter<<<(emax + NT - 1) / NT, NT, 0, stream>>>(head, tail, edge_type, e_kg,
                                                     iu, ii, inter_w, e_ui, cur, comb, n_ent);
  // degree-bucket sort of segments
  k_bhist<<<128, NT, 0, stream>>>(deg, bh, n_ent, n_seg);
  k_bscan<<<1, 128, 0, stream>>>(bh);
  k_bscatter<<<128, NT, 0, stream>>>(deg, bh, perm, n_ent, n_seg);

  float* res_e = out;
  float* res_u = out + (size_t)n_ent * 128;
  int agg_blocks = (n_seg + 15) / 16;  // 16 segments per 256-thread block

  // hop 0: gemm reads fp32 entity_emb (fused cvt), agg writes nextPC only (entities)
  k_gemm<<<256, NT, 0, stream>>>(PCa, entity_emb, W_Q, PCa, n_ent);
  k_agg<<<agg_blocks, NT, 0, stream>>>(PCa, offs, comb, perm, rel_emb, entity_emb, user_emb,
                                       PCb, res_e, res_u, n_ent, n_seg, 1);
  // hop 1: gemm reads PCb cur-half (hop0 output), agg finalizes residuals
  k_gemm<<<256, NT, 0, stream>>>(PCb, nullptr, W_Q, PCb, n_ent);
  k_agg<<<agg_blocks, NT, 0, stream>>>(PCb, offs, comb, perm, rel_emb, entity_emb, nullptr,
                                       nullptr, res_e, res_u, n_ent, n_seg, 0);
}

// Round 7
// 652.324 us; speedup vs baseline: 2.5648x; 1.0020x over previous
//
#include <hip/hip_runtime.h>
#include <math.h>

#define NT 256
typedef unsigned short u16;
typedef __attribute__((ext_vector_type(8))) u16 u16x8;
typedef __attribute__((ext_vector_type(4))) u16 u16x4;
typedef __attribute__((ext_vector_type(8))) short bf16x8;
typedef __attribute__((ext_vector_type(4))) float f32x4;
typedef __attribute__((ext_vector_type(2))) float f32x2;

// PC row layout (stride 384 B): [0,128) fp8-e4m3 P (score side) | [128,384) bf16 cur (value side)
#define PCS 384

__device__ __forceinline__ float bf2f(u16 h) {
  union { unsigned u; float f; } v;
  v.u = ((unsigned)h) << 16;
  return v.f;
}
__device__ __forceinline__ u16 f2bf(float f) {
  union { float f; unsigned u; } v;
  v.f = f;
  unsigned r = v.u + 0x7FFFu + ((v.u >> 16) & 1u);
  return (u16)(r >> 16);
}

// ---------------- CSR build (combined entity+user) ----------------
__global__ __launch_bounds__(NT) void k_hist(const int* __restrict__ head, int n_kg,
                                             const int* __restrict__ usr, int n_ui,
                                             int* __restrict__ deg, int n_ent) {
  int i = blockIdx.x * NT + threadIdx.x;
  if (i < n_kg) atomicAdd(&deg[head[i]], 1);
  if (i < n_ui) atomicAdd(&deg[n_ent + usr[i]], 1);
}

__global__ __launch_bounds__(NT) void k_scan1(const int* __restrict__ in, int* __restrict__ out,
                                              int* __restrict__ aux, int n) {
  __shared__ int sd[NT];
  int t = threadIdx.x;
  int base = blockIdx.x * (NT * 8) + t * 8;
  int v[8], ex[8];
  int run = 0;
#pragma unroll
  for (int j = 0; j < 8; ++j) {
    v[j] = (base + j < n) ? in[base + j] : 0;
    ex[j] = run;
    run += v[j];
  }
  sd[t] = run;
  __syncthreads();
  for (int off = 1; off < NT; off <<= 1) {
    int x = (t >= off) ? sd[t - off] : 0;
    __syncthreads();
    sd[t] += x;
    __syncthreads();
  }
  int texcl = sd[t] - run;
#pragma unroll
  for (int j = 0; j < 8; ++j)
    if (base + j < n) out[base + j] = texcl + ex[j];
  if (t == NT - 1) aux[blockIdx.x] = sd[NT - 1];
}

__global__ __launch_bounds__(NT) void k_scan2(int* __restrict__ aux, int nb) {
  __shared__ int sd[NT];
  int t = threadIdx.x;
  int v = (t < nb) ? aux[t] : 0;
  sd[t] = v;
  __syncthreads();
  for (int off = 1; off < NT; off <<= 1) {
    int x = (t >= off) ? sd[t - off] : 0;
    __syncthreads();
    sd[t] += x;
    __syncthreads();
  }
  if (t < nb) aux[t] = sd[t] - v;  // exclusive
}

__global__ __launch_bounds__(NT) void k_scan3(int* __restrict__ out, int* __restrict__ cur,
                                              const int* __restrict__ aux, int n) {
  int base = blockIdx.x * (NT * 8) + threadIdx.x * 8;
  int add = aux[blockIdx.x];
#pragma unroll
  for (int j = 0; j < 8; ++j)
    if (base + j < n) {
      int v = out[base + j] + add;
      out[base + j] = v;
      cur[base + j] = v;
    }
}

__global__ __launch_bounds__(NT) void k_scatter(
    const int* __restrict__ head, const int* __restrict__ tail, const int* __restrict__ etype, int n_kg,
    const int* __restrict__ usr, const int* __restrict__ item, const float* __restrict__ w, int n_ui,
    int* __restrict__ cursor, int* __restrict__ comb, int n_ent) {
  int i = blockIdx.x * NT + threadIdx.x;
  if (i < n_kg) {
    int p = atomicAdd(&cursor[head[i]], 1);
    comb[p] = tail[i] | ((etype[i] - 1) << 20);
  }
  if (i < n_ui) {
    int p = atomicAdd(&cursor[n_ent + usr[i]], 1);
    int wq = (int)(w[i] * 16383.0f + 0.5f);
    if (wq > 16383) wq = 16383;
    comb[p] = (int)(((unsigned)item[i]) | (((unsigned)wq) << 18));
  }
}

// ---------------- degree-bucket sort of segments (type-pure, descending) ----------------
__device__ __forceinline__ int seg_bin(int deg, int i, int n_ent) {
  int d = deg < 63 ? deg : 63;
  return (i < n_ent ? 0 : 64) + 63 - d;
}

__global__ __launch_bounds__(NT) void k_bhist(const int* __restrict__ deg, int* __restrict__ bh,
                                              int n_ent, int n_seg) {
  __shared__ int lh[128];
  if (threadIdx.x < 128) lh[threadIdx.x] = 0;
  __syncthreads();
  for (int i = blockIdx.x * NT + threadIdx.x; i < n_seg; i += gridDim.x * NT)
    atomicAdd(&lh[seg_bin(deg[i], i, n_ent)], 1);
  __syncthreads();
  if (threadIdx.x < 128) atomicAdd(&bh[threadIdx.x], lh[threadIdx.x]);
}

__global__ __launch_bounds__(128) void k_bscan(int* __restrict__ bh) {
  __shared__ int sd[128];
  int t = threadIdx.x;
  int v = bh[t];
  sd[t] = v;
  __syncthreads();
  for (int off = 1; off < 128; off <<= 1) {
    int x = (t >= off) ? sd[t - off] : 0;
    __syncthreads();
    sd[t] += x;
    __syncthreads();
  }
  bh[t] = sd[t] - v;  // exclusive
}

__global__ __launch_bounds__(NT) void k_bscatter(const int* __restrict__ deg, int* __restrict__ bcur,
                                                 int* __restrict__ perm, int n_ent, int n_seg) {
  __shared__ int lh[128], lbase[128];
  if (threadIdx.x < 128) lh[threadIdx.x] = 0;
  __syncthreads();
  int start = blockIdx.x * NT + threadIdx.x, stride = gridDim.x * NT;
  for (int i = start; i < n_seg; i += stride)
    atomicAdd(&lh[seg_bin(deg[i], i, n_ent)], 1);
  __syncthreads();
  if (threadIdx.x < 128) {
    lbase[threadIdx.x] = atomicAdd(&bcur[threadIdx.x], lh[threadIdx.x]);
    lh[threadIdx.x] = 0;
  }
  __syncthreads();
  for (int i = start; i < n_seg; i += stride) {
    int b = seg_bin(deg[i], i, n_ent);
    int off = atomicAdd(&lh[b], 1);
    perm[lbase[b] + off] = i;
  }
}

// ---------------- MFMA GEMM: P-half(PC, fp8) = A @ W ----------------
// A32 != nullptr: hop0 -- A from fp32 entity_emb; also writes bf16 cur-half.
// Else A = cur-half (bf16) of PCin.
__global__ __launch_bounds__(NT) void k_gemm(const char* __restrict__ PCin, const float* __restrict__ A32,
                                             const float* __restrict__ W, char* __restrict__ PCout, int M) {
  __shared__ u16 WT[128 * 136];  // W^T[n][k] bf16
  for (int i = threadIdx.x; i < 128 * 32; i += NT) {
    int n = i & 127, k4 = (i >> 7) << 2;
    u16x4 o = {f2bf(W[(k4 + 0) * 128 + n]), f2bf(W[(k4 + 1) * 128 + n]),
               f2bf(W[(k4 + 2) * 128 + n]), f2bf(W[(k4 + 3) * 128 + n])};
    *(u16x4*)&WT[n * 136 + k4] = o;
  }
  __syncthreads();
  int lane = threadIdx.x & 63;
  int l15 = lane & 15, l4 = lane >> 4;
  int wave = blockIdx.x * (NT / 64) + (threadIdx.x >> 6);
  int nw = gridDim.x * (NT / 64);
  int ntiles = (M + 15) >> 4;
  for (int tile = wave; tile < ntiles; tile += nw) {
    long row0 = (long)tile * 16;
    long myrow = row0 + l15;
    bool rowok = myrow < M;
    long ar = rowok ? myrow : (long)(M - 1);
    bf16x8 af[4];
    if (A32) {
      const float* arow = A32 + ar * 128;
#pragma unroll
      for (int kk = 0; kk < 4; ++kk) {
        const float* p = arow + kk * 32 + l4 * 8;
        float4 f0 = *(const float4*)p;
        float4 f1 = *(const float4*)(p + 4);
        u16x8 t = {f2bf(f0.x), f2bf(f0.y), f2bf(f0.z), f2bf(f0.w),
                   f2bf(f1.x), f2bf(f1.y), f2bf(f1.z), f2bf(f1.w)};
        af[kk] = *(bf16x8*)&t;
        if (rowok) *(u16x8*)(PCout + ar * PCS + 128 + kk * 64 + l4 * 16) = t;
      }
    } else {
      const char* arow = PCin + ar * PCS + 128;  // cur half (bf16)
#pragma unroll
      for (int kk = 0; kk < 4; ++kk) af[kk] = *(const bf16x8*)(arow + kk * 64 + l4 * 16);
    }
    f32x4 acc[8];
#pragma unroll
    for (int nt = 0; nt < 8; ++nt) acc[nt] = (f32x4){0.f, 0.f, 0.f, 0.f};
#pragma unroll
    for (int kk = 0; kk < 4; ++kk) {
#pragma unroll
      for (int nt = 0; nt < 8; ++nt) {
        bf16x8 bf = *(const bf16x8*)&WT[(nt * 16 + l15) * 136 + kk * 32 + l4 * 8];
        acc[nt] = __builtin_amdgcn_mfma_f32_16x16x32_bf16(af[kk], bf, acc[nt], 0, 0, 0);
      }
    }
#pragma unroll
    for (int nt = 0; nt < 8; ++nt) {
#pragma unroll
      for (int j = 0; j < 4; ++j) {
        long row = row0 + l4 * 4 + j;
        if (row < M) {
          float v = acc[nt][j];
          int pk = __builtin_amdgcn_cvt_pk_fp8_f32(v, v, 0, false);
          PCout[row * PCS + nt * 16 + l15] = (char)(pk & 0xFF);
        }
      }
    }
  }
}

// ---------------- fused segment aggregate (entity attention + user) ----------------
// One 16-lane unit per segment; 4 degree-matched segments per wave (perm).
// fp8 score-side gathers (8B/lane), bf16 value gathers (16B/lane).
// Distance-4 software pipeline, masked tail steps (clamped addrs hit cache).
__global__ __launch_bounds__(NT) void k_agg(
    const char* __restrict__ PCc, const int* __restrict__ offs, const int* __restrict__ comb,
    const int* __restrict__ perm, const float* __restrict__ rel_emb,
    const float* __restrict__ base_e, const float* __restrict__ base_u,
    char* __restrict__ nextPC, float* __restrict__ res_e, float* __restrict__ res_u,
    int n_ent, int n_seg, int hop0) {
  __shared__ float rel[9 * 128];
  for (int i = threadIdx.x; i < 9 * 128; i += NT) rel[i] = rel_emb[i];
  __syncthreads();
  int lane = threadIdx.x & 63;
  int unit = lane >> 4;
  int cl = lane & 15;    // channel chunk (8 ch); head = cl>>3
  int chb = cl * 8;
  int vid = (((blockIdx.x * NT + threadIdx.x) >> 6) << 2) + unit;
  if (vid >= n_seg) return;
  int sseg = perm[vid];
  int beg = offs[sseg], end = offs[sseg + 1];
  int cnt = end - beg;

#define EGATHER(TE, PV, CV)                                           \
  do {                                                                \
    const char* rowp = PCc + (size_t)((TE) & 0xFFFFF) * PCS;          \
    PV = *(const uint2*)(rowp + (cl << 3));                           \
    CV = *(const u16x8*)(rowp + 128 + (cl << 4));                     \
  } while (0)

#define ESTEP(TE, PV, CV, VALID)                                              \
  do {                                                                        \
    const float* rp = &rel[((TE) >> 20) * 128 + chb];                         \
    float4 rA = *(const float4*)rp;                                           \
    float4 rB = *(const float4*)(rp + 4);                                     \
    f32x2 p01 = __builtin_amdgcn_cvt_pk_f32_fp8((int)(PV).x, false);          \
    f32x2 p23 = __builtin_amdgcn_cvt_pk_f32_fp8((int)(PV).x, true);           \
    f32x2 p45 = __builtin_amdgcn_cvt_pk_f32_fp8((int)(PV).y, false);          \
    f32x2 p67 = __builtin_amdgcn_cvt_pk_f32_fp8((int)(PV).y, true);           \
    float pp = q[0] * p01[0] * rA.x + q[1] * p01[1] * rA.y +                  \
               q[2] * p23[0] * rA.z + q[3] * p23[1] * rA.w +                  \
               q[4] * p45[0] * rB.x + q[5] * p45[1] * rB.y +                  \
               q[6] * p67[0] * rB.z + q[7] * p67[1] * rB.w;                   \
    pp += __shfl_xor(pp, 1);                                                  \
    pp += __shfl_xor(pp, 2);                                                  \
    pp += __shfl_xor(pp, 4);                                                  \
    float e = (VALID) ? __expf(pp) : 0.f;                                     \
    s += e;                                                                   \
    a[0] = fmaf(bf2f((CV)[0]) * rA.x, e, a[0]);                               \
    a[1] = fmaf(bf2f((CV)[1]) * rA.y, e, a[1]);                               \
    a[2] = fmaf(bf2f((CV)[2]) * rA.z, e, a[2]);                               \
    a[3] = fmaf(bf2f((CV)[3]) * rA.w, e, a[3]);                               \
    a[4] = fmaf(bf2f((CV)[4]) * rB.x, e, a[4]);                               \
    a[5] = fmaf(bf2f((CV)[5]) * rB.y, e, a[5]);                               \
    a[6] = fmaf(bf2f((CV)[6]) * rB.z, e, a[6]);                               \
    a[7] = fmaf(bf2f((CV)[7]) * rB.w, e, a[7]);                               \
  } while (0)

  if (sseg < n_ent) {
    // ---- entity attention path ----
    uint2 qv = *(const uint2*)(PCc + (size_t)sseg * PCS + (cl << 3));
    f32x2 q01 = __builtin_amdgcn_cvt_pk_f32_fp8((int)qv.x, false);
    f32x2 q23 = __builtin_amdgcn_cvt_pk_f32_fp8((int)qv.x, true);
    f32x2 q45 = __builtin_amdgcn_cvt_pk_f32_fp8((int)qv.y, false);
    f32x2 q67 = __builtin_amdgcn_cvt_pk_f32_fp8((int)qv.y, true);
    float q[8] = {q01[0] * 0.125f, q01[1] * 0.125f, q23[0] * 0.125f, q23[1] * 0.125f,
                  q45[0] * 0.125f, q45[1] * 0.125f, q67[0] * 0.125f, q67[1] * 0.125f};
    float s = 0.f;
    float a[8] = {0.f, 0.f, 0.f, 0.f, 0.f, 0.f, 0.f, 0.f};
    if (cnt > 0) {
      int last = cnt - 1;
#define TEL(k) ((unsigned)comb[beg + ((k) < last ? (k) : last)])
      unsigned tA = TEL(0), tB = TEL(1), tC2 = TEL(2), tD = TEL(3);
      uint2 PA, PB, PCv, PD;
      u16x8 CA, CB, CC, CD;
      EGATHER(tA, PA, CA);
      EGATHER(tB, PB, CB);
      EGATHER(tC2, PCv, CC);
      EGATHER(tD, PD, CD);
      int i = 0;
      while (i < cnt) {
        unsigned tE = TEL(i + 4), tF = TEL(i + 5), tG = TEL(i + 6), tH = TEL(i + 7);
        ESTEP(tA, PA, CA, true);
        EGATHER(tE, PA, CA);
        ESTEP(tB, PB, CB, i + 1 < cnt);
        EGATHER(tF, PB, CB);
        ESTEP(tC2, PCv, CC, i + 2 < cnt);
        EGATHER(tG, PCv, CC);
        ESTEP(tD, PD, CD, i + 3 < cnt);
        EGATHER(tH, PD, CD);
        tA = tE; tB = tF; tC2 = tG; tD = tH;
        i += 4;
      }
#undef TEL
    }
    float invs = 1.0f / fmaxf(s, 1e-16f);
    float gv[8];
    float nr = 0.f;
#pragma unroll
    for (int j = 0; j < 8; ++j) {
      gv[j] = a[j] * invs;
      nr += gv[j] * gv[j];
    }
    nr += __shfl_xor(nr, 1);
    nr += __shfl_xor(nr, 2);
    nr += __shfl_xor(nr, 4);
    nr += __shfl_xor(nr, 8);
    float inv = 1.0f / fmaxf(sqrtf(nr), 1e-12f);
#pragma unroll
    for (int j = 0; j < 8; ++j) gv[j] *= inv;
    if (hop0) {
      u16x8 o;
#pragma unroll
      for (int j = 0; j < 8; ++j) o[j] = f2bf(gv[j]);
      *(u16x8*)(nextPC + (size_t)sseg * PCS + 128 + (cl << 4)) = o;
    } else {
      u16x8 g0 = *(const u16x8*)(PCc + (size_t)sseg * PCS + 128 + (cl << 4));
      size_t o4 = (size_t)sseg * 128 + (size_t)chb;
      float4 b0 = *(const float4*)(base_e + o4);
      float4 b1 = *(const float4*)(base_e + o4 + 4);
      float4 w0 = {b0.x + bf2f(g0[0]) + gv[0], b0.y + bf2f(g0[1]) + gv[1],
                   b0.z + bf2f(g0[2]) + gv[2], b0.w + bf2f(g0[3]) + gv[3]};
      float4 w1 = {b1.x + bf2f(g0[4]) + gv[4], b1.y + bf2f(g0[5]) + gv[5],
                   b1.z + bf2f(g0[6]) + gv[6], b1.w + bf2f(g0[7]) + gv[7]};
      *(float4*)(res_e + o4) = w0;
      *(float4*)(res_e + o4 + 4) = w1;
    }
  } else {
    // ---- user aggregate path ----
    int u = sseg - n_ent;
    float a[8] = {0.f, 0.f, 0.f, 0.f, 0.f, 0.f, 0.f, 0.f};
#define UGATHER(IW, CV) \
  CV = *(const u16x8*)(PCc + (size_t)((IW) & 0x3FFFF) * PCS + 128 + (cl << 4))
#define USTEP(IW, CV, VALID)                                              \
  do {                                                                    \
    float ww = (VALID) ? (float)((IW) >> 18) * (1.0f / 16383.0f) : 0.f;   \
    _Pragma("unroll") for (int j = 0; j < 8; ++j)                         \
        a[j] = fmaf(bf2f((CV)[j]), ww, a[j]);                             \
  } while (0)
    if (cnt > 0) {
      int last = cnt - 1;
#define TEL(k) ((unsigned)comb[beg + ((k) < last ? (k) : last)])
      unsigned tA = TEL(0), tB = TEL(1), tC2 = TEL(2), tD = TEL(3);
      u16x8 CA, CB, CC, CD;
      UGATHER(tA, CA);
      UGATHER(tB, CB);
      UGATHER(tC2, CC);
      UGATHER(tD, CD);
      int i = 0;
      while (i < cnt) {
        unsigned tE = TEL(i + 4), tF = TEL(i + 5), tG = TEL(i + 6), tH = TEL(i + 7);
        USTEP(tA, CA, true);
        UGATHER(tE, CA);
        USTEP(tB, CB, i + 1 < cnt);
        UGATHER(tF, CB);
        USTEP(tC2, CC, i + 2 < cnt);
        UGATHER(tG, CC);
        USTEP(tD, CD, i + 3 < cnt);
        UGATHER(tH, CD);
        tA = tE; tB = tF; tC2 = tG; tD = tH;
        i += 4;
      }
#undef TEL
    }
    float nr = 0.f;
#pragma unroll
    for (int j = 0; j < 8; ++j) nr += a[j] * a[j];
    nr += __shfl_xor(nr, 1);
    nr += __shfl_xor(nr, 2);
    nr += __shfl_xor(nr, 4);
    nr += __shfl_xor(nr, 8);
    float inv = 1.0f / fmaxf(sqrtf(nr), 1e-12f);
    size_t o = (size_t)u * 128 + (size_t)chb;
    const float* bp = hop0 ? (base_u + o) : (res_u + o);
    float4 r0 = *(const float4*)bp;
    float4 r1 = *(const float4*)(bp + 4);
    r0.x += a[0] * inv; r0.y += a[1] * inv; r0.z += a[2] * inv; r0.w += a[3] * inv;
    r1.x += a[4] * inv; r1.y += a[5] * inv; r1.z += a[6] * inv; r1.w += a[7] * inv;
    *(float4*)(res_u + o) = r0;
    *(float4*)(res_u + o + 4) = r1;
  }
}

// ---------------- host ----------------
extern "C" void kernel_launch(void* const* d_in, const int* in_sizes, int n_in,
                              void* d_out, int out_size, void* d_ws, size_t ws_size,
                              hipStream_t stream) {
  const float* user_emb = (const float*)d_in[0];
  const float* entity_emb = (const float*)d_in[1];
  const int* edge_index = (const int*)d_in[2];
  const int* edge_type = (const int*)d_in[3];
  const int* inter_edge = (const int*)d_in[4];
  const float* inter_w = (const float*)d_in[5];
  const float* rel_emb = (const float*)d_in[6];
  const float* W_Q = (const float*)d_in[7];
  float* out = (float*)d_out;

  int n_users = in_sizes[0] / 128;
  int n_ent = in_sizes[1] / 128;
  int e_kg = in_sizes[3];
  int e_ui = in_sizes[5];
  const int* head = edge_index;
  const int* tail = edge_index + e_kg;
  const int* iu = inter_edge;         // users
  const int* ii = inter_edge + e_ui;  // items

  int n_seg = n_ent + n_users;

  // workspace carve
  char* wp = (char*)d_ws;
  auto take = [&](size_t bytes) {
    char* p = wp;
    wp += (bytes + 255) & ~(size_t)255;
    return p;
  };
  char* PCa = take((size_t)n_ent * PCS);
  char* PCb = take((size_t)n_ent * PCS);
  int* deg = (int*)take((size_t)(n_seg + 1) * 4);
  int* offs = (int*)take((size_t)(n_seg + 1) * 4);
  int* cur = (int*)take((size_t)(n_seg + 1) * 4);
  int* comb = (int*)take((size_t)(e_kg + e_ui) * 4);
  int* perm = (int*)take((size_t)n_seg * 4);
  int* bh = (int*)take(512);
  int* aux = (int*)take(1024);
  (void)ws_size;
  (void)n_in;
  (void)out_size;

  // combined CSR build (shared by both hops)
  hipMemsetAsync(deg, 0, (size_t)(n_seg + 1) * 4, stream);
  hipMemsetAsync(bh, 0, 512, stream);
  int emax = e_kg > e_ui ? e_kg : e_ui;
  k_hist<<<(emax + NT - 1) / NT, NT, 0, stream>>>(head, e_kg, iu, e_ui, deg, n_ent);
  int nscan = n_seg + 1;
  int nb = (nscan + NT * 8 - 1) / (NT * 8);
  k_scan1<<<nb, NT, 0, stream>>>(deg, offs, aux, nscan);
  k_scan2<<<1, NT, 0, stream>>>(aux, nb);
  k_scan3<<<nb, NT, 0, stream>>>(offs, cur, aux, nscan);
  k_scatter<<<(emax + NT - 1) / NT, NT, 0, stream>>>(head, tail, edge_type, e_kg,
                                                     iu, ii, inter_w, e_ui, cur, comb, n_ent);
  // degree-bucket sort of segments
  k_bhist<<<128, NT, 0, stream>>>(deg, bh, n_ent, n_seg);
  k_bscan<<<1, 128, 0, stream>>>(bh);
  k_bscatter<<<128, NT, 0, stream>>>(deg, bh, perm, n_ent, n_seg);

  float* res_e = out;
  float* res_u = out + (size_t)n_ent * 128;
  int agg_blocks = (n_seg + 15) / 16;

  // hop 0: gemm reads fp32 entity_emb (fused cvt), agg writes nextPC only (entities)
  k_gemm<<<256, NT, 0, stream>>>(PCa, entity_emb, W_Q, PCa, n_ent);
  k_agg<<<agg_blocks, NT, 0, stream>>>(PCa, offs, comb, perm, rel_emb, entity_emb, user_emb,
                                       PCb, res_e, res_u, n_ent, n_seg, 1);
  // hop 1: gemm reads PCb cur-half, agg finalizes residuals
  k_gemm<<<256, NT, 0, stream>>>(PCb, nullptr, W_Q, PCb, n_ent);
  k_agg<<<agg_blocks, NT, 0, stream>>>(PCb, offs, comb, perm, rel_emb, entity_emb, nullptr,
                                       nullptr, res_e, res_u, n_ent, n_seg, 0);
}